// Round 1
// baseline (940.458 us; speedup 1.0000x reference)
//
#include <hip/hip_runtime.h>

namespace {
constexpr int SD = 1024;           // D
constexpr int TD = 2048;           // 2D
constexpr int BATCH = 8;
constexpr int IDIM = 64;
constexpr int RH = 4;
constexpr float EPSc = 1e-5f;
constexpr float DXf = 2.0f / 31.0f;
constexpr float DXDYf = DXf * DXf;
constexpr float SCALEf = 0.125f;
constexpr float CFINAL = DXDYf * DXDYf * SCALEf;

// workspace offsets (in floats); all multiples of 4 -> float4 safe
constexpr size_t OFF_V   = 0;
constexpr size_t OFF_MID = OFF_V   + (size_t)BATCH * TD * IDIM;   // 1048576
constexpr size_t OFF_W   = OFF_MID + (size_t)BATCH * TD * IDIM;
constexpr size_t OFF_WF  = OFF_W   + (size_t)SD * SD;
constexpr size_t OFF_U1K = OFF_WF  + (size_t)SD * SD;
constexpr size_t OFF_U2K = OFF_U1K + SD * 32;
constexpr size_t OFF_U1F = OFF_U2K + SD * 32;
constexpr size_t OFF_U2F = OFF_U1F + SD * 32;
constexpr size_t OFF_GP  = OFF_U2F + SD * 32;                      // 8*32*4096
constexpr size_t OFF_SP  = OFF_GP  + (size_t)BATCH * 32 * 4096;    // 8*32*64
constexpr size_t OFF_G   = OFF_SP  + BATCH * 32 * 64;
constexpr size_t OFF_SV  = OFF_G   + BATCH * 4096;
constexpr size_t OFF_PM  = OFF_SV  + BATCH * 64;                   // 8*4*4096
constexpr size_t OFF_RP  = OFF_PM  + (size_t)BATCH * RH * 4096;
constexpr size_t OFF_A   = OFF_RP  + BATCH * RH * 64;
constexpr size_t OFF_RV  = OFF_A   + BATCH * 4096;
constexpr size_t OFF_LNP = OFF_RV  + BATCH * 64;                   // 8*32*2
constexpr size_t OFF_ST  = OFF_LNP + BATCH * 32 * 2;               // 16
constexpr size_t OFF_ZU  = OFF_ST  + 16;
constexpr size_t OFF_ZF  = OFF_ZU  + (size_t)SD * 512;
constexpr size_t OFF_W1  = OFF_ZF  + (size_t)SD * 512;
constexpr size_t WS_FLOATS = OFF_W1 + SD;
} // namespace

__device__ __forceinline__ float leaky(float x) { return x > 0.0f ? x : 0.01f * x; }
__device__ __forceinline__ float gxv(int i) { return -1.0f + (2.0f / 31.0f) * (float)i; }

// ---- edge-MLP layer-1 factorization tables ----
__global__ void k_pre_u(const float* __restrict__ kW1, const float* __restrict__ kb1,
                        const float* __restrict__ fW1, const float* __restrict__ fb1,
                        float* __restrict__ u1k, float* __restrict__ u2k,
                        float* __restrict__ u1f, float* __restrict__ u2f) {
  int n = blockIdx.x * blockDim.x + threadIdx.x;
  if (n >= SD) return;
  float ga = gxv(n >> 5), gb = gxv(n & 31);
  for (int j = 0; j < 32; j++) {
    u1k[n * 32 + j] = ga * kW1[j] + gb * kW1[32 + j] + kb1[j];
    u2k[n * 32 + j] = gb * kW1[64 + j] + ga * kW1[96 + j];
    u1f[n * 32 + j] = ga * fW1[j] + gb * fW1[32 + j] + fb1[j];
    u2f[n * 32 + j] = gb * fW1[64 + j] + ga * fW1[96 + j];
  }
}

// ---- per-edge MLP: h1=leaky(u1[n]+u2[m]); h2=leaky(h1@W2+b2); w=h2@W3+b3 ----
__global__ __launch_bounds__(256) void k_mlp(const float* __restrict__ u1, const float* __restrict__ u2,
                                             const float* __restrict__ W2, const float* __restrict__ b2,
                                             const float* __restrict__ W3, const float* __restrict__ b3,
                                             float* __restrict__ out) {
  __shared__ __align__(16) float sW2[2048];
  __shared__ float sW3[64];
  __shared__ float sb2[64];
  __shared__ float su1[4 * 32];
  __shared__ float su2[64 * 33];  // padded stride 33 -> no bank conflict
  int tx = threadIdx.x;           // m local (0..63)
  int ty = threadIdx.y;           // n local (0..3)
  int t = ty * 64 + tx;
  int mtile = blockIdx.x * 64;
  int ntile = blockIdx.y * 4;
  for (int k = t; k < 2048; k += 256) sW2[k] = W2[k];
  if (t < 64) { sW3[t] = W3[t]; sb2[t] = b2[t]; }
  if (t < 128) su1[t] = u1[ntile * 32 + t];
  for (int k = t; k < 2048; k += 256) su2[(k >> 5) * 33 + (k & 31)] = u2[mtile * 32 + k];
  __syncthreads();

  float h1[32];
#pragma unroll
  for (int j = 0; j < 32; j++) h1[j] = leaky(su1[ty * 32 + j] + su2[tx * 33 + j]);
  float acc[64];
#pragma unroll
  for (int o = 0; o < 64; o++) acc[o] = sb2[o];
#pragma unroll
  for (int j = 0; j < 32; j++) {
    float hv = h1[j];
    const float4* w4 = reinterpret_cast<const float4*>(&sW2[j * 64]);
#pragma unroll
    for (int o4 = 0; o4 < 16; o4++) {
      float4 w = w4[o4];
      acc[o4 * 4 + 0] += hv * w.x; acc[o4 * 4 + 1] += hv * w.y;
      acc[o4 * 4 + 2] += hv * w.z; acc[o4 * 4 + 3] += hv * w.w;
    }
  }
  float wsum = b3[0];
#pragma unroll
  for (int o = 0; o < 64; o++) wsum += leaky(acc[o]) * sW3[o];
  out[(size_t)(ntile + ty) * SD + mtile + tx] = wsum;
}

// ---- column sums of W and Wf combined: w1[c] = sum_n (W[n][c]+Wf[n][c]) ----
__global__ void k_colsum(const float* __restrict__ W, const float* __restrict__ Wf,
                         float* __restrict__ w1) {
  int c = blockIdx.x * blockDim.x + threadIdx.x;
  if (c >= SD) return;
  float s = 0.f;
  for (int n = 0; n < SD; n++) s += W[(size_t)n * SD + c] + Wf[(size_t)n * SD + c];
  w1[c] = s;
}

// ---- LN partial sums (per batch, 32 chunks of 4096) ----
__global__ __launch_bounds__(256) void k_redsum(const float* __restrict__ X, float* __restrict__ part) {
  int b = blockIdx.y, c = blockIdx.x, t = threadIdx.x;
  const float4* X4 = reinterpret_cast<const float4*>(X + (size_t)b * 131072 + (size_t)c * 4096);
  float s = 0.f, q = 0.f;
#pragma unroll
  for (int k = 0; k < 4; k++) {
    float4 v = X4[t + k * 256];
    s += v.x + v.y + v.z + v.w;
    q += v.x * v.x + v.y * v.y + v.z * v.z + v.w * v.w;
  }
  for (int off = 32; off; off >>= 1) { s += __shfl_down(s, off); q += __shfl_down(q, off); }
  __shared__ float ss[4], qq[4];
  int lane = t & 63, wid = t >> 6;
  if (lane == 0) { ss[wid] = s; qq[wid] = q; }
  __syncthreads();
  if (t == 0) {
    part[(size_t)(b * gridDim.x + c) * 2] = ss[0] + ss[1] + ss[2] + ss[3];
    part[(size_t)(b * gridDim.x + c) * 2 + 1] = qq[0] + qq[1] + qq[2] + qq[3];
  }
}

__global__ void k_stats(const float* __restrict__ part, float* __restrict__ stats, int nch) {
  int t = threadIdx.x;
  if (t < BATCH) {
    float s = 0.f, q = 0.f;
    for (int c = 0; c < nch; c++) { s += part[(size_t)(t * nch + c) * 2]; q += part[(size_t)(t * nch + c) * 2 + 1]; }
    float mean = s / 131072.0f;
    float var = q / 131072.0f - mean * mean;
    stats[t * 2] = mean;
    stats[t * 2 + 1] = rsqrtf(var + EPSc);
  }
}

// ---- apply LN: dst = (src-mean)*invstd*g + b (+ addv) ----
__global__ __launch_bounds__(256) void k_apply(const float* __restrict__ src, const float* __restrict__ g,
                                               const float* __restrict__ bb, const float* __restrict__ stats,
                                               const float* __restrict__ addv, float* __restrict__ dst) {
  int i4 = blockIdx.x * 256 + threadIdx.x;  // 0..262143
  int b = i4 >> 15;
  int p4 = i4 & 32767;
  float mean = stats[b * 2], is = stats[b * 2 + 1];
  float4 v = reinterpret_cast<const float4*>(src)[i4];
  float4 gg = reinterpret_cast<const float4*>(g)[p4];
  float4 bv = reinterpret_cast<const float4*>(bb)[p4];
  float4 r;
  r.x = (v.x - mean) * is * gg.x + bv.x;
  r.y = (v.y - mean) * is * gg.y + bv.y;
  r.z = (v.z - mean) * is * gg.z + bv.z;
  r.w = (v.w - mean) * is * gg.w + bv.w;
  if (addv != nullptr) {
    float4 av = reinterpret_cast<const float4*>(addv)[i4];
    r.x += av.x; r.y += av.y; r.z += av.z; r.w += av.w;
  }
  reinterpret_cast<float4*>(dst)[i4] = r;
}

// ---- chunked X^T Y (64 rows per chunk) + colsum(Y) partials ----
__global__ __launch_bounds__(256) void k_xty(const float* __restrict__ Xb, const float* __restrict__ Yb,
                                             float* __restrict__ Gp, float* __restrict__ sp) {
  int c = blockIdx.x, b = blockIdx.y, t = threadIdx.x;
  int nch = gridDim.x;
  const float4* X4 = reinterpret_cast<const float4*>(Xb + (size_t)b * 131072 + (size_t)c * 4096);
  const float4* Y4 = reinterpret_cast<const float4*>(Yb + (size_t)b * 131072 + (size_t)c * 4096);
  __shared__ __align__(16) float Xs[4096];
  __shared__ __align__(16) float Ys[4096];
#pragma unroll
  for (int k = 0; k < 4; k++) {
    reinterpret_cast<float4*>(Xs)[t + k * 256] = X4[t + k * 256];
    reinterpret_cast<float4*>(Ys)[t + k * 256] = Y4[t + k * 256];
  }
  __syncthreads();
  int p = t >> 2, qb = (t & 3) * 16;
  float4 acc[4] = {};
  for (int k = 0; k < 64; k++) {
    float xv = Xs[k * 64 + p];
    const float4* y = reinterpret_cast<const float4*>(&Ys[k * 64 + qb]);
#pragma unroll
    for (int u = 0; u < 4; u++) {
      float4 yv = y[u];
      acc[u].x += xv * yv.x; acc[u].y += xv * yv.y; acc[u].z += xv * yv.z; acc[u].w += xv * yv.w;
    }
  }
  float* go = Gp + (size_t)(b * nch + c) * 4096 + p * 64 + qb;
#pragma unroll
  for (int u = 0; u < 4; u++) reinterpret_cast<float4*>(go)[u] = acc[u];
  if (t < 64) {
    float ssum = 0.f;
    for (int k = 0; k < 64; k++) ssum += Ys[k * 64 + t];
    sp[(size_t)(b * nch + c) * 64 + t] = ssum;
  }
}

__global__ void k_xty_red(const float* __restrict__ Gp, const float* __restrict__ sp,
                          float* __restrict__ G, float* __restrict__ sv, int nch) {
  int b = blockIdx.x, t = threadIdx.x;
  for (int j = 0; j < 16; j++) {
    int idx = j * 256 + t;
    float a = 0.f;
    for (int c = 0; c < nch; c++) a += Gp[(size_t)(b * nch + c) * 4096 + idx];
    G[(size_t)b * 4096 + idx] = a;
  }
  if (t < 64) {
    float a = 0.f;
    for (int c = 0; c < nch; c++) a += sp[(size_t)(b * nch + c) * 64 + t];
    sv[b * 64 + t] = a;
  }
}

// ---- per (head i, batch b): M = Wk_i^T G + bk_i(x)s ; P_i = Wq_i M ; r_i = bq_i^T M ----
__global__ __launch_bounds__(256) void k_heads(const float* __restrict__ G, const float* __restrict__ sv,
                                               const float* __restrict__ Wq, const float* __restrict__ bq,
                                               const float* __restrict__ Wk, const float* __restrict__ bk,
                                               float* __restrict__ Pm, float* __restrict__ Rp) {
  int i = blockIdx.x, b = blockIdx.y, t = threadIdx.x;
  __shared__ __align__(16) float Gs[4096];
  __shared__ __align__(16) float Ms[4096];
  __shared__ float ssv[64];
  const float4* G4 = reinterpret_cast<const float4*>(G + (size_t)b * 4096);
#pragma unroll
  for (int k = 0; k < 4; k++) reinterpret_cast<float4*>(Gs)[t + k * 256] = G4[t + k * 256];
  if (t < 64) ssv[t] = sv[b * 64 + t];
  __syncthreads();
  int kk = t >> 2, qb = (t & 3) * 16;
  float4 acc[4] = {};
  const float* wkc = Wk + (size_t)i * 4096 + kk;  // Wk[i][c][kk], stride 64 over c
  for (int c = 0; c < 64; c++) {
    float wv = wkc[c * 64];
    const float4* gr = reinterpret_cast<const float4*>(&Gs[c * 64 + qb]);
#pragma unroll
    for (int u = 0; u < 4; u++) {
      float4 gv = gr[u];
      acc[u].x += wv * gv.x; acc[u].y += wv * gv.y; acc[u].z += wv * gv.z; acc[u].w += wv * gv.w;
    }
  }
  float bkv = bk[i * 64 + kk];
#pragma unroll
  for (int u = 0; u < 4; u++) {
    acc[u].x += bkv * ssv[qb + u * 4 + 0];
    acc[u].y += bkv * ssv[qb + u * 4 + 1];
    acc[u].z += bkv * ssv[qb + u * 4 + 2];
    acc[u].w += bkv * ssv[qb + u * 4 + 3];
  }
#pragma unroll
  for (int u = 0; u < 4; u++) reinterpret_cast<float4*>(&Ms[kk * 64 + qb])[u] = acc[u];
  __syncthreads();
  // phase 2: P[c][q] = sum_k Wq[c][k]*M[k][q]
  int cc = t >> 2;
  float4 acc2[4] = {};
  const float* wqc = Wq + (size_t)i * 4096 + cc * 64;  // Wq[i][cc][k]
  for (int k2 = 0; k2 < 64; k2++) {
    float wv = wqc[k2];
    const float4* mr = reinterpret_cast<const float4*>(&Ms[k2 * 64 + qb]);
#pragma unroll
    for (int u = 0; u < 4; u++) {
      float4 mv = mr[u];
      acc2[u].x += wv * mv.x; acc2[u].y += wv * mv.y; acc2[u].z += wv * mv.z; acc2[u].w += wv * mv.w;
    }
  }
  float* po = Pm + (size_t)(b * RH + i) * 4096 + cc * 64 + qb;
#pragma unroll
  for (int u = 0; u < 4; u++) reinterpret_cast<float4*>(po)[u] = acc2[u];
  if (t < 64) {
    float a = 0.f;
    for (int k2 = 0; k2 < 64; k2++) a += bq[i * 64 + k2] * Ms[k2 * 64 + t];
    Rp[(b * RH + i) * 64 + t] = a;
  }
}

__global__ void k_heads_red(const float* __restrict__ Pm, const float* __restrict__ Rp,
                            float* __restrict__ A, float* __restrict__ rv, float scale) {
  int b = blockIdx.x, t = threadIdx.x;
  for (int j = 0; j < 16; j++) {
    int idx = j * 256 + t;
    float a = 0.f;
    for (int i = 0; i < RH; i++) a += Pm[(size_t)(b * RH + i) * 4096 + idx];
    A[(size_t)b * 4096 + idx] = a * scale;
  }
  if (t < 64) {
    float a = 0.f;
    for (int i = 0; i < RH; i++) a += Rp[(b * RH + i) * 64 + t];
    rv[b * 64 + t] = a * scale;
  }
}

// ---- mid = V @ A + 1 r^T (scale pre-folded), with fused LN partials ----
__global__ __launch_bounds__(256) void k_mid(const float* __restrict__ V, const float* __restrict__ A,
                                             const float* __restrict__ rv, float* __restrict__ mid,
                                             float* __restrict__ lnp) {
  int blk = blockIdx.x, b = blockIdx.y, t = threadIdx.x;
  __shared__ __align__(16) float As[4096];
  __shared__ float rs[64];
  const float4* A4 = reinterpret_cast<const float4*>(A + (size_t)b * 4096);
#pragma unroll
  for (int k = 0; k < 4; k++) reinterpret_cast<float4*>(As)[t + k * 256] = A4[t + k * 256];
  if (t < 64) rs[t] = rv[b * 64 + t];
  __syncthreads();
  int row = blk * 64 + (t >> 2), qb = (t & 3) * 16;
  const float* vr = V + (size_t)b * 131072 + (size_t)row * 64;
  float4 acc[4];
#pragma unroll
  for (int u = 0; u < 4; u++) {
    acc[u].x = rs[qb + u * 4 + 0]; acc[u].y = rs[qb + u * 4 + 1];
    acc[u].z = rs[qb + u * 4 + 2]; acc[u].w = rs[qb + u * 4 + 3];
  }
  for (int c = 0; c < 64; c++) {
    float vv = vr[c];
    const float4* ar = reinterpret_cast<const float4*>(&As[c * 64 + qb]);
#pragma unroll
    for (int u = 0; u < 4; u++) {
      float4 av = ar[u];
      acc[u].x += vv * av.x; acc[u].y += vv * av.y; acc[u].z += vv * av.z; acc[u].w += vv * av.w;
    }
  }
  float* mo = mid + (size_t)b * 131072 + (size_t)row * 64 + qb;
#pragma unroll
  for (int u = 0; u < 4; u++) reinterpret_cast<float4*>(mo)[u] = acc[u];
  // LN partials over this block's 64 rows
  float s = 0.f, q = 0.f;
#pragma unroll
  for (int u = 0; u < 4; u++) {
    s += acc[u].x + acc[u].y + acc[u].z + acc[u].w;
    q += acc[u].x * acc[u].x + acc[u].y * acc[u].y + acc[u].z * acc[u].z + acc[u].w * acc[u].w;
  }
  for (int off = 32; off; off >>= 1) { s += __shfl_down(s, off); q += __shfl_down(q, off); }
  __shared__ float ss[4], qq[4];
  int lane = t & 63, wid = t >> 6;
  if (lane == 0) { ss[wid] = s; qq[wid] = q; }
  __syncthreads();
  if (t == 0) {
    lnp[(size_t)(b * 32 + blk) * 2] = ss[0] + ss[1] + ss[2] + ss[3];
    lnp[(size_t)(b * 32 + blk) * 2 + 1] = qq[0] + qq[1] + qq[2] + qq[3];
  }
}

// ---- Z[m][b*64+q] = sum_c V[b][rowOffset+m][c] * C[b][c][q] ----
__global__ __launch_bounds__(256) void k_y(const float* __restrict__ V, const float* __restrict__ A,
                                           float* __restrict__ Z, int rowOffset) {
  int blk = blockIdx.x, b = blockIdx.y, t = threadIdx.x;
  __shared__ __align__(16) float As[4096];
  const float4* A4 = reinterpret_cast<const float4*>(A + (size_t)b * 4096);
#pragma unroll
  for (int k = 0; k < 4; k++) reinterpret_cast<float4*>(As)[t + k * 256] = A4[t + k * 256];
  __syncthreads();
  int m = blk * 64 + (t >> 2), qb = (t & 3) * 16;
  const float* vr = V + (size_t)b * 131072 + (size_t)(rowOffset + m) * 64;
  float4 acc[4] = {};
  for (int c = 0; c < 64; c++) {
    float vv = vr[c];
    const float4* ar = reinterpret_cast<const float4*>(&As[c * 64 + qb]);
#pragma unroll
    for (int u = 0; u < 4; u++) {
      float4 av = ar[u];
      acc[u].x += vv * av.x; acc[u].y += vv * av.y; acc[u].z += vv * av.z; acc[u].w += vv * av.w;
    }
  }
  float* zo = Z + (size_t)m * 512 + b * 64 + qb;
#pragma unroll
  for (int u = 0; u < 4; u++) reinterpret_cast<float4*>(zo)[u] = acc[u];
}

// ---- out[b][n'][i'] = CF*( sum_m W[m][n']Zu[m][b*64+i'] + Wf·Zf + w1[n']*d[b][i'] ) ----
__global__ __launch_bounds__(256) void k_final(const float* __restrict__ W, const float* __restrict__ Wf,
                                               const float* __restrict__ Zu, const float* __restrict__ Zf,
                                               const float* __restrict__ w1, const float* __restrict__ dv,
                                               float* __restrict__ out) {
  int tn = blockIdx.x, b = blockIdx.y, t = threadIdx.x;
  int ntile = tn * 64;
  __shared__ __align__(16) float Ws[4096];
  __shared__ __align__(16) float Zs[4096];
  int ip = t & 63, wid = t >> 6;
  float acc[16] = {};
  for (int pass = 0; pass < 2; pass++) {
    const float4* Wp = pass ? reinterpret_cast<const float4*>(Wf) : reinterpret_cast<const float4*>(W);
    const float4* Zp = pass ? reinterpret_cast<const float4*>(Zf) : reinterpret_cast<const float4*>(Zu);
    for (int mt = 0; mt < 16; mt++) {
      __syncthreads();
#pragma unroll
      for (int k = 0; k < 4; k++) {
        int f4 = t + k * 256;
        int ml = f4 >> 4, nl4 = f4 & 15;
        reinterpret_cast<float4*>(Ws)[f4] = Wp[(size_t)(mt * 64 + ml) * 256 + (ntile >> 2) + nl4];
        reinterpret_cast<float4*>(Zs)[f4] = Zp[(size_t)(mt * 64 + ml) * 128 + b * 16 + nl4];
      }
      __syncthreads();
      for (int ml = 0; ml < 64; ml++) {
        float zv = Zs[ml * 64 + ip];
        const float4* wr = reinterpret_cast<const float4*>(&Ws[ml * 64 + wid * 16]);
#pragma unroll
        for (int u = 0; u < 4; u++) {
          float4 wv = wr[u];
          acc[u * 4 + 0] += wv.x * zv; acc[u * 4 + 1] += wv.y * zv;
          acc[u * 4 + 2] += wv.z * zv; acc[u * 4 + 3] += wv.w * zv;
        }
      }
    }
  }
  float dvv = dv[b * 64 + ip];
  float* op = out + (size_t)b * 65536 + (size_t)ntile * 64;
#pragma unroll
  for (int u = 0; u < 16; u++) {
    int nl = wid * 16 + u;
    op[(size_t)nl * 64 + ip] = CFINAL * (acc[u] + w1[ntile + nl] * dvv);
  }
}

extern "C" void kernel_launch(void* const* d_in, const int* in_sizes, int n_in,
                              void* d_out, int out_size, void* d_ws, size_t ws_size,
                              hipStream_t stream) {
  (void)in_sizes; (void)n_in; (void)out_size;
  const float* xy  = (const float*)d_in[1];
  const float* kW1 = (const float*)d_in[3];
  const float* kb1 = (const float*)d_in[4];
  const float* kW2 = (const float*)d_in[5];
  const float* kb2 = (const float*)d_in[6];
  const float* kW3 = (const float*)d_in[7];
  const float* kb3 = (const float*)d_in[8];
  const float* fW1 = (const float*)d_in[9];
  const float* fb1 = (const float*)d_in[10];
  const float* fW2 = (const float*)d_in[11];
  const float* fb2 = (const float*)d_in[12];
  const float* fW3 = (const float*)d_in[13];
  const float* fb3 = (const float*)d_in[14];
  const float* Wq  = (const float*)d_in[15];
  const float* bq  = (const float*)d_in[16];
  const float* Wk  = (const float*)d_in[17];
  const float* bk  = (const float*)d_in[18];
  const float* lng = (const float*)d_in[19];
  const float* lnb = (const float*)d_in[20];
  float* ws = (float*)d_ws;
  float* out = (float*)d_out;
  if (ws_size < WS_FLOATS * sizeof(float)) return;  // visible failure, no OOB

  float* V   = ws + OFF_V;
  float* MID = ws + OFF_MID;
  float* Wm  = ws + OFF_W;
  float* Wfm = ws + OFF_WF;
  float* U1K = ws + OFF_U1K;
  float* U2K = ws + OFF_U2K;
  float* U1F = ws + OFF_U1F;
  float* U2F = ws + OFF_U2F;
  float* GP  = ws + OFF_GP;
  float* SP  = ws + OFF_SP;
  float* G   = ws + OFF_G;
  float* SV  = ws + OFF_SV;
  float* PM  = ws + OFF_PM;
  float* RP  = ws + OFF_RP;
  float* A   = ws + OFF_A;
  float* RV  = ws + OFF_RV;
  float* LNP = ws + OFF_LNP;
  float* ST  = ws + OFF_ST;
  float* ZU  = ws + OFF_ZU;
  float* ZF  = ws + OFF_ZF;
  float* W1v = ws + OFF_W1;

  k_pre_u<<<dim3(4), dim3(256), 0, stream>>>(kW1, kb1, fW1, fb1, U1K, U2K, U1F, U2F);
  k_mlp<<<dim3(16, 256), dim3(64, 4), 0, stream>>>(U1K, U2K, kW2, kb2, kW3, kb3, Wm);
  k_mlp<<<dim3(16, 256), dim3(64, 4), 0, stream>>>(U1F, U2F, fW2, fb2, fW3, fb3, Wfm);
  k_colsum<<<dim3(4), dim3(256), 0, stream>>>(Wm, Wfm, W1v);

  k_redsum<<<dim3(32, 8), dim3(256), 0, stream>>>(xy, LNP);
  k_stats<<<1, 64, 0, stream>>>(LNP, ST, 32);
  k_apply<<<dim3(1024), dim3(256), 0, stream>>>(xy, lng, lnb, ST, nullptr, V);

  for (int j = 0; j < 2; j++) {
    k_xty<<<dim3(32, 8), dim3(256), 0, stream>>>(V, V, GP, SP);
    k_xty_red<<<dim3(8), dim3(256), 0, stream>>>(GP, SP, G, SV, 32);
    k_heads<<<dim3(4, 8), dim3(256), 0, stream>>>(G, SV, Wq + (size_t)j * RH * 4096, bq + j * RH * 64,
                                                  Wk + (size_t)j * RH * 4096, bk + j * RH * 64, PM, RP);
    k_heads_red<<<dim3(8), dim3(256), 0, stream>>>(PM, RP, A, RV, DXDYf * SCALEf);
    k_mid<<<dim3(32, 8), dim3(256), 0, stream>>>(V, A, RV, MID, LNP);
    k_stats<<<1, 64, 0, stream>>>(LNP, ST, 32);
    k_apply<<<dim3(1024), dim3(256), 0, stream>>>(MID, lng + (size_t)(j + 1) * 131072,
                                                  lnb + (size_t)(j + 1) * 131072, ST, V, V);
  }

  // final block: H = V_u^T xy_d, t = colsum(xy_d)
  k_xty<<<dim3(16, 8), dim3(256), 0, stream>>>(V, xy, GP, SP);
  k_xty_red<<<dim3(8), dim3(256), 0, stream>>>(GP, SP, G, SV, 16);
  k_heads<<<dim3(4, 8), dim3(256), 0, stream>>>(G, SV, Wq + (size_t)2 * RH * 4096, bq + 2 * RH * 64,
                                                Wk + (size_t)2 * RH * 4096, bk + 2 * RH * 64, PM, RP);
  k_heads_red<<<dim3(8), dim3(256), 0, stream>>>(PM, RP, A, RV, 1.0f);
  k_y<<<dim3(16, 8), dim3(256), 0, stream>>>(V, A, ZU, 0);
  k_y<<<dim3(16, 8), dim3(256), 0, stream>>>(V, A, ZF, 1024);
  k_final<<<dim3(16, 8), dim3(256), 0, stream>>>(Wm, Wfm, ZU, ZF, W1v, RV, out);
}

// Round 2
// 807.120 us; speedup vs baseline: 1.1652x; 1.1652x over previous
//
#include <hip/hip_runtime.h>

namespace {
constexpr int SD = 1024;           // D
constexpr int TD = 2048;           // 2D
constexpr int BATCH = 8;
constexpr int IDIM = 64;
constexpr int RH = 4;
constexpr float EPSc = 1e-5f;
constexpr float DXf = 2.0f / 31.0f;
constexpr float DXDYf = DXf * DXf;
constexpr float SCALEf = 0.125f;
constexpr float CFINAL = DXDYf * DXDYf * SCALEf;

// workspace offsets (in floats); all multiples of 4 -> float4 safe
constexpr size_t OFF_V   = 0;
constexpr size_t OFF_MID = OFF_V   + (size_t)BATCH * TD * IDIM;   // 1048576 floats; reused as FP after loop
constexpr size_t OFF_W   = OFF_MID + (size_t)BATCH * TD * IDIM;
constexpr size_t OFF_WF  = OFF_W   + (size_t)SD * SD;
constexpr size_t OFF_U1K = OFF_WF  + (size_t)SD * SD;
constexpr size_t OFF_U2K = OFF_U1K + SD * 32;
constexpr size_t OFF_U1F = OFF_U2K + SD * 32;
constexpr size_t OFF_U2F = OFF_U1F + SD * 32;
constexpr size_t OFF_GP  = OFF_U2F + SD * 32;                      // 8*32*4096
constexpr size_t OFF_SP  = OFF_GP  + (size_t)BATCH * 32 * 4096;    // 8*32*64
constexpr size_t OFF_A   = OFF_SP  + BATCH * 32 * 64;
constexpr size_t OFF_RV  = OFF_A   + BATCH * 4096;
constexpr size_t OFF_LNP = OFF_RV  + BATCH * 64;                   // 8*32*2
constexpr size_t OFF_ZU  = OFF_LNP + BATCH * 32 * 2;               // ZU,ZF contiguous
constexpr size_t OFF_ZF  = OFF_ZU  + (size_t)SD * 512;
constexpr size_t OFF_W1  = OFF_ZF  + (size_t)SD * 512;
constexpr size_t OFF_CS  = OFF_W1  + SD;                           // 16*1024 colsum partials
constexpr size_t WS_FLOATS = OFF_CS + 16 * SD;
} // namespace

__device__ __forceinline__ float leaky(float x) { return x > 0.0f ? x : 0.01f * x; }
__device__ __forceinline__ float gxv(int i) { return -1.0f + (2.0f / 31.0f) * (float)i; }

// ---- edge-MLP layer-1 factorization tables ----
__global__ void k_pre_u(const float* __restrict__ kW1, const float* __restrict__ kb1,
                        const float* __restrict__ fW1, const float* __restrict__ fb1,
                        float* __restrict__ u1k, float* __restrict__ u2k,
                        float* __restrict__ u1f, float* __restrict__ u2f) {
  int n = blockIdx.x * blockDim.x + threadIdx.x;
  if (n >= SD) return;
  float ga = gxv(n >> 5), gb = gxv(n & 31);
  for (int j = 0; j < 32; j++) {
    u1k[n * 32 + j] = ga * kW1[j] + gb * kW1[32 + j] + kb1[j];
    u2k[n * 32 + j] = gb * kW1[64 + j] + ga * kW1[96 + j];
    u1f[n * 32 + j] = ga * fW1[j] + gb * fW1[32 + j] + fb1[j];
    u2f[n * 32 + j] = gb * fW1[64 + j] + ga * fW1[96 + j];
  }
}

// ---- per-edge MLP: h1=leaky(u1[n]+u2[m]); h2=leaky(h1@W2+b2); w=h2@W3+b3 ----
__global__ __launch_bounds__(256) void k_mlp(const float* __restrict__ u1, const float* __restrict__ u2,
                                             const float* __restrict__ W2, const float* __restrict__ b2,
                                             const float* __restrict__ W3, const float* __restrict__ b3,
                                             float* __restrict__ out) {
  __shared__ __align__(16) float sW2[2048];
  __shared__ float sW3[64];
  __shared__ float sb2[64];
  __shared__ float su1[4 * 32];
  __shared__ float su2[64 * 33];  // padded stride 33 -> no bank conflict
  int tx = threadIdx.x;           // m local (0..63)
  int ty = threadIdx.y;           // n local (0..3)
  int t = ty * 64 + tx;
  int mtile = blockIdx.x * 64;
  int ntile = blockIdx.y * 4;
  for (int k = t; k < 2048; k += 256) sW2[k] = W2[k];
  if (t < 64) { sW3[t] = W3[t]; sb2[t] = b2[t]; }
  if (t < 128) su1[t] = u1[ntile * 32 + t];
  for (int k = t; k < 2048; k += 256) su2[(k >> 5) * 33 + (k & 31)] = u2[mtile * 32 + k];
  __syncthreads();

  float h1[32];
#pragma unroll
  for (int j = 0; j < 32; j++) h1[j] = leaky(su1[ty * 32 + j] + su2[tx * 33 + j]);
  float acc[64];
#pragma unroll
  for (int o = 0; o < 64; o++) acc[o] = sb2[o];
#pragma unroll
  for (int j = 0; j < 32; j++) {
    float hv = h1[j];
    const float4* w4 = reinterpret_cast<const float4*>(&sW2[j * 64]);
#pragma unroll
    for (int o4 = 0; o4 < 16; o4++) {
      float4 w = w4[o4];
      acc[o4 * 4 + 0] += hv * w.x; acc[o4 * 4 + 1] += hv * w.y;
      acc[o4 * 4 + 2] += hv * w.z; acc[o4 * 4 + 3] += hv * w.w;
    }
  }
  float wsum = b3[0];
#pragma unroll
  for (int o = 0; o < 64; o++) wsum += leaky(acc[o]) * sW3[o];
  out[(size_t)(ntile + ty) * SD + mtile + tx] = wsum;
}

// ---- colsum stage 1: cs[r][c] = sum over 64 rows of (W+Wf) ----
__global__ __launch_bounds__(256) void k_colsum_p1(const float* __restrict__ W, const float* __restrict__ Wf,
                                                   float* __restrict__ cs) {
  int c = blockIdx.x * 256 + threadIdx.x;
  int n0 = blockIdx.y * 64;
  float s = 0.f;
  for (int r = 0; r < 64; r++) s += W[(size_t)(n0 + r) * SD + c] + Wf[(size_t)(n0 + r) * SD + c];
  cs[blockIdx.y * SD + c] = s;
}

__global__ __launch_bounds__(256) void k_colsum_p2(const float* __restrict__ cs, float* __restrict__ w1) {
  int c = blockIdx.x * 256 + threadIdx.x;
  float s = 0.f;
#pragma unroll
  for (int r = 0; r < 16; r++) s += cs[r * SD + c];
  w1[c] = s;
}

// ---- LN partial sums (per batch, 32 chunks of 4096) ----
__global__ __launch_bounds__(256) void k_redsum(const float* __restrict__ X, float* __restrict__ part) {
  int b = blockIdx.y, c = blockIdx.x, t = threadIdx.x;
  const float4* X4 = reinterpret_cast<const float4*>(X + (size_t)b * 131072 + (size_t)c * 4096);
  float s = 0.f, q = 0.f;
#pragma unroll
  for (int k = 0; k < 4; k++) {
    float4 v = X4[t + k * 256];
    s += v.x + v.y + v.z + v.w;
    q += v.x * v.x + v.y * v.y + v.z * v.z + v.w * v.w;
  }
  for (int off = 32; off; off >>= 1) { s += __shfl_down(s, off); q += __shfl_down(q, off); }
  __shared__ float ss[4], qq[4];
  int lane = t & 63, wid = t >> 6;
  if (lane == 0) { ss[wid] = s; qq[wid] = q; }
  __syncthreads();
  if (t == 0) {
    part[(size_t)(b * 32 + c) * 2] = ss[0] + ss[1] + ss[2] + ss[3];
    part[(size_t)(b * 32 + c) * 2 + 1] = qq[0] + qq[1] + qq[2] + qq[3];
  }
}

// ---- apply LN (stats computed inline from 32 partials): dst = (src-mean)*invstd*g + b (+ addv) ----
__global__ __launch_bounds__(256) void k_apply(const float* __restrict__ src, const float* __restrict__ g,
                                               const float* __restrict__ bb, const float* __restrict__ lnp,
                                               const float* __restrict__ addv, float* __restrict__ dst) {
  __shared__ float sm[2];
  int i4 = blockIdx.x * 256 + threadIdx.x;  // 0..262143
  int b = i4 >> 15;                          // uniform within block (128 blocks/batch)
  if (threadIdx.x == 0) {
    float s = 0.f, q = 0.f;
    for (int c = 0; c < 32; c++) { s += lnp[(size_t)(b * 32 + c) * 2]; q += lnp[(size_t)(b * 32 + c) * 2 + 1]; }
    float mean = s / 131072.0f;
    sm[0] = mean;
    sm[1] = rsqrtf(q / 131072.0f - mean * mean + EPSc);
  }
  __syncthreads();
  float mean = sm[0], is = sm[1];
  int p4 = i4 & 32767;
  float4 v = reinterpret_cast<const float4*>(src)[i4];
  float4 gg = reinterpret_cast<const float4*>(g)[p4];
  float4 bv = reinterpret_cast<const float4*>(bb)[p4];
  float4 r;
  r.x = (v.x - mean) * is * gg.x + bv.x;
  r.y = (v.y - mean) * is * gg.y + bv.y;
  r.z = (v.z - mean) * is * gg.z + bv.z;
  r.w = (v.w - mean) * is * gg.w + bv.w;
  if (addv != nullptr) {
    float4 av = reinterpret_cast<const float4*>(addv)[i4];
    r.x += av.x; r.y += av.y; r.z += av.z; r.w += av.w;
  }
  reinterpret_cast<float4*>(dst)[i4] = r;
}

// ---- chunked X^T Y (64 rows per chunk) + colsum(Y) partials ----
__global__ __launch_bounds__(256) void k_xty(const float* __restrict__ Xb, const float* __restrict__ Yb,
                                             float* __restrict__ Gp, float* __restrict__ sp) {
  int c = blockIdx.x, b = blockIdx.y, t = threadIdx.x;
  int nch = gridDim.x;
  const float4* X4 = reinterpret_cast<const float4*>(Xb + (size_t)b * 131072 + (size_t)c * 4096);
  const float4* Y4 = reinterpret_cast<const float4*>(Yb + (size_t)b * 131072 + (size_t)c * 4096);
  __shared__ __align__(16) float Xs[4096];
  __shared__ __align__(16) float Ys[4096];
#pragma unroll
  for (int k = 0; k < 4; k++) {
    reinterpret_cast<float4*>(Xs)[t + k * 256] = X4[t + k * 256];
    reinterpret_cast<float4*>(Ys)[t + k * 256] = Y4[t + k * 256];
  }
  __syncthreads();
  int p = t >> 2, qb = (t & 3) * 16;
  float4 acc[4] = {};
  for (int k = 0; k < 64; k++) {
    float xv = Xs[k * 64 + p];
    const float4* y = reinterpret_cast<const float4*>(&Ys[k * 64 + qb]);
#pragma unroll
    for (int u = 0; u < 4; u++) {
      float4 yv = y[u];
      acc[u].x += xv * yv.x; acc[u].y += xv * yv.y; acc[u].z += xv * yv.z; acc[u].w += xv * yv.w;
    }
  }
  float* go = Gp + (size_t)(b * nch + c) * 4096 + p * 64 + qb;
#pragma unroll
  for (int u = 0; u < 4; u++) reinterpret_cast<float4*>(go)[u] = acc[u];
  if (t < 64) {
    float ssum = 0.f;
    for (int k = 0; k < 64; k++) ssum += Ys[k * 64 + t];
    sp[(size_t)(b * nch + c) * 64 + t] = ssum;
  }
}

// ---- fused: reduce G partials; for each head i: M = Wk_i^T G + bk_i(x)s; A += Wq_i M; r += bq_i^T M ----
__global__ __launch_bounds__(256) void k_heads_f(const float* __restrict__ Gp, const float* __restrict__ sp,
                                                 const float* __restrict__ Wq, const float* __restrict__ bq,
                                                 const float* __restrict__ Wk, const float* __restrict__ bk,
                                                 float* __restrict__ A, float* __restrict__ rv,
                                                 int nch, float scale) {
  int b = blockIdx.x, t = threadIdx.x;
  __shared__ __align__(16) float Gs[4096];
  __shared__ __align__(16) float Ms[4096];
  __shared__ float ssv[64];
  for (int j = 0; j < 16; j++) {
    int idx = j * 256 + t;
    float a = 0.f;
    for (int c = 0; c < nch; c++) a += Gp[(size_t)(b * nch + c) * 4096 + idx];
    Gs[idx] = a;
  }
  if (t < 64) {
    float a = 0.f;
    for (int c = 0; c < nch; c++) a += sp[(size_t)(b * nch + c) * 64 + t];
    ssv[t] = a;
  }
  __syncthreads();

  int kk = t >> 2, qb = (t & 3) * 16;   // phase-1 roles
  float4 accA[4] = {};                   // phase-2 accumulators (persist over heads)
  float accR = 0.f;                      // t<64: r[q=t]
  for (int i = 0; i < RH; i++) {
    float4 acc[4] = {};
    const float* wkc = Wk + (size_t)i * 4096 + kk;  // Wk[i][c][kk], stride 64 over c
    for (int c = 0; c < 64; c++) {
      float wv = wkc[c * 64];
      const float4* gr = reinterpret_cast<const float4*>(&Gs[c * 64 + qb]);
#pragma unroll
      for (int u = 0; u < 4; u++) {
        float4 gv = gr[u];
        acc[u].x += wv * gv.x; acc[u].y += wv * gv.y; acc[u].z += wv * gv.z; acc[u].w += wv * gv.w;
      }
    }
    float bkv = bk[i * 64 + kk];
#pragma unroll
    for (int u = 0; u < 4; u++) {
      acc[u].x += bkv * ssv[qb + u * 4 + 0];
      acc[u].y += bkv * ssv[qb + u * 4 + 1];
      acc[u].z += bkv * ssv[qb + u * 4 + 2];
      acc[u].w += bkv * ssv[qb + u * 4 + 3];
    }
    __syncthreads();  // previous head's Ms reads complete
#pragma unroll
    for (int u = 0; u < 4; u++) reinterpret_cast<float4*>(&Ms[kk * 64 + qb])[u] = acc[u];
    __syncthreads();
    // accumulate P[c][q] += sum_k Wq[i][c][k]*M[k][q]
    const float* wqc = Wq + (size_t)i * 4096 + kk * 64;  // Wq[i][cc=kk][k]
    for (int k2 = 0; k2 < 64; k2++) {
      float wv = wqc[k2];
      const float4* mr = reinterpret_cast<const float4*>(&Ms[k2 * 64 + qb]);
#pragma unroll
      for (int u = 0; u < 4; u++) {
        float4 mv = mr[u];
        accA[u].x += wv * mv.x; accA[u].y += wv * mv.y; accA[u].z += wv * mv.z; accA[u].w += wv * mv.w;
      }
    }
    if (t < 64) {
      float a = 0.f;
      for (int k2 = 0; k2 < 64; k2++) a += bq[i * 64 + k2] * Ms[k2 * 64 + t];
      accR += a;
    }
  }
  float* po = A + (size_t)b * 4096 + kk * 64 + qb;
#pragma unroll
  for (int u = 0; u < 4; u++) {
    float4 v = accA[u];
    v.x *= scale; v.y *= scale; v.z *= scale; v.w *= scale;
    reinterpret_cast<float4*>(po)[u] = v;
  }
  if (t < 64) rv[b * 64 + t] = accR * scale;
}

// ---- mid = V @ A + 1 r^T (scale pre-folded), with fused LN partials ----
__global__ __launch_bounds__(256) void k_mid(const float* __restrict__ V, const float* __restrict__ A,
                                             const float* __restrict__ rv, float* __restrict__ mid,
                                             float* __restrict__ lnp) {
  int blk = blockIdx.x, b = blockIdx.y, t = threadIdx.x;
  __shared__ __align__(16) float As[4096];
  __shared__ float rs[64];
  const float4* A4 = reinterpret_cast<const float4*>(A + (size_t)b * 4096);
#pragma unroll
  for (int k = 0; k < 4; k++) reinterpret_cast<float4*>(As)[t + k * 256] = A4[t + k * 256];
  if (t < 64) rs[t] = rv[b * 64 + t];
  __syncthreads();
  int row = blk * 64 + (t >> 2), qb = (t & 3) * 16;
  const float* vr = V + (size_t)b * 131072 + (size_t)row * 64;
  float4 acc[4];
#pragma unroll
  for (int u = 0; u < 4; u++) {
    acc[u].x = rs[qb + u * 4 + 0]; acc[u].y = rs[qb + u * 4 + 1];
    acc[u].z = rs[qb + u * 4 + 2]; acc[u].w = rs[qb + u * 4 + 3];
  }
  for (int c = 0; c < 64; c++) {
    float vv = vr[c];
    const float4* ar = reinterpret_cast<const float4*>(&As[c * 64 + qb]);
#pragma unroll
    for (int u = 0; u < 4; u++) {
      float4 av = ar[u];
      acc[u].x += vv * av.x; acc[u].y += vv * av.y; acc[u].z += vv * av.z; acc[u].w += vv * av.w;
    }
  }
  float* mo = mid + (size_t)b * 131072 + (size_t)row * 64 + qb;
#pragma unroll
  for (int u = 0; u < 4; u++) reinterpret_cast<float4*>(mo)[u] = acc[u];
  float s = 0.f, q = 0.f;
#pragma unroll
  for (int u = 0; u < 4; u++) {
    s += acc[u].x + acc[u].y + acc[u].z + acc[u].w;
    q += acc[u].x * acc[u].x + acc[u].y * acc[u].y + acc[u].z * acc[u].z + acc[u].w * acc[u].w;
  }
  for (int off = 32; off; off >>= 1) { s += __shfl_down(s, off); q += __shfl_down(q, off); }
  __shared__ float ss[4], qq[4];
  int lane = t & 63, wid = t >> 6;
  if (lane == 0) { ss[wid] = s; qq[wid] = q; }
  __syncthreads();
  if (t == 0) {
    lnp[(size_t)(b * 32 + blk) * 2] = ss[0] + ss[1] + ss[2] + ss[3];
    lnp[(size_t)(b * 32 + blk) * 2 + 1] = qq[0] + qq[1] + qq[2] + qq[3];
  }
}

// ---- Z[z][m][b*64+q] = sum_c V[b][z*1024+m][c] * A[b][c][q] ----
__global__ __launch_bounds__(256) void k_y(const float* __restrict__ V, const float* __restrict__ A,
                                           float* __restrict__ Z) {
  int blk = blockIdx.x, b = blockIdx.y, z = blockIdx.z, t = threadIdx.x;
  __shared__ __align__(16) float As[4096];
  const float4* A4 = reinterpret_cast<const float4*>(A + (size_t)b * 4096);
#pragma unroll
  for (int k = 0; k < 4; k++) reinterpret_cast<float4*>(As)[t + k * 256] = A4[t + k * 256];
  __syncthreads();
  int m = blk * 64 + (t >> 2), qb = (t & 3) * 16;
  const float* vr = V + (size_t)b * 131072 + (size_t)(z * 1024 + m) * 64;
  float4 acc[4] = {};
  for (int c = 0; c < 64; c++) {
    float vv = vr[c];
    const float4* ar = reinterpret_cast<const float4*>(&As[c * 64 + qb]);
#pragma unroll
    for (int u = 0; u < 4; u++) {
      float4 av = ar[u];
      acc[u].x += vv * av.x; acc[u].y += vv * av.y; acc[u].z += vv * av.z; acc[u].w += vv * av.w;
    }
  }
  float* zo = Z + (size_t)z * 524288 + (size_t)m * 512 + b * 64 + qb;
#pragma unroll
  for (int u = 0; u < 4; u++) reinterpret_cast<float4*>(zo)[u] = acc[u];
}

// ---- final GEMM partial: FP[h][b][n][i] = sum_m Wh[m][n] * Zh[m][b*64+i] ----
__global__ __launch_bounds__(256) void k_final_part(const float* __restrict__ W, const float* __restrict__ Wf,
                                                    const float* __restrict__ Z, float* __restrict__ FP) {
  int tn = blockIdx.x, b = blockIdx.y, h = blockIdx.z, t = threadIdx.x;
  int ntile = tn * 64;
  const float4* Wp = reinterpret_cast<const float4*>(h ? Wf : W);
  const float4* Zp = reinterpret_cast<const float4*>(Z + (size_t)h * 524288);
  __shared__ __align__(16) float Ws[4096];
  __shared__ __align__(16) float Zs[4096];
  int ip = t & 63, wid = t >> 6;
  float acc[16] = {};
  for (int mt = 0; mt < 16; mt++) {
    __syncthreads();
#pragma unroll
    for (int k = 0; k < 4; k++) {
      int f4 = t + k * 256;
      int ml = f4 >> 4, nl4 = f4 & 15;
      reinterpret_cast<float4*>(Ws)[f4] = Wp[(size_t)(mt * 64 + ml) * 256 + (ntile >> 2) + nl4];
      reinterpret_cast<float4*>(Zs)[f4] = Zp[(size_t)(mt * 64 + ml) * 128 + b * 16 + nl4];
    }
    __syncthreads();
    for (int ml = 0; ml < 64; ml++) {
      float zv = Zs[ml * 64 + ip];
      const float4* wr = reinterpret_cast<const float4*>(&Ws[ml * 64 + wid * 16]);
#pragma unroll
      for (int u = 0; u < 4; u++) {
        float4 wv = wr[u];
        acc[u * 4 + 0] += wv.x * zv; acc[u * 4 + 1] += wv.y * zv;
        acc[u * 4 + 2] += wv.z * zv; acc[u * 4 + 3] += wv.w * zv;
      }
    }
  }
  float* op = FP + (size_t)h * 524288 + (size_t)b * 65536 + (size_t)ntile * 64;
#pragma unroll
  for (int u = 0; u < 16; u++) {
    int nl = wid * 16 + u;
    op[(size_t)nl * 64 + ip] = acc[u];
  }
}

// ---- out = CFINAL * (FP0 + FP1 + w1[n]*dv[b][i]) ----
__global__ __launch_bounds__(256) void k_final_red(const float* __restrict__ FP, const float* __restrict__ w1,
                                                   const float* __restrict__ dv, float* __restrict__ out) {
  int idx4 = blockIdx.x * 256 + threadIdx.x;  // 0..131071 (float4 over out)
  int i4p = idx4 & 15;
  int n = (idx4 >> 4) & 1023;
  int b = idx4 >> 14;
  float4 a = reinterpret_cast<const float4*>(FP)[idx4];
  float4 c = reinterpret_cast<const float4*>(FP)[idx4 + 131072];
  float4 d = reinterpret_cast<const float4*>(dv)[b * 16 + i4p];
  float wv = w1[n];
  float4 r;
  r.x = CFINAL * (a.x + c.x + wv * d.x);
  r.y = CFINAL * (a.y + c.y + wv * d.y);
  r.z = CFINAL * (a.z + c.z + wv * d.z);
  r.w = CFINAL * (a.w + c.w + wv * d.w);
  reinterpret_cast<float4*>(out)[idx4] = r;
}

extern "C" void kernel_launch(void* const* d_in, const int* in_sizes, int n_in,
                              void* d_out, int out_size, void* d_ws, size_t ws_size,
                              hipStream_t stream) {
  (void)in_sizes; (void)n_in; (void)out_size;
  const float* xy  = (const float*)d_in[1];
  const float* kW1 = (const float*)d_in[3];
  const float* kb1 = (const float*)d_in[4];
  const float* kW2 = (const float*)d_in[5];
  const float* kb2 = (const float*)d_in[6];
  const float* kW3 = (const float*)d_in[7];
  const float* kb3 = (const float*)d_in[8];
  const float* fW1 = (const float*)d_in[9];
  const float* fb1 = (const float*)d_in[10];
  const float* fW2 = (const float*)d_in[11];
  const float* fb2 = (const float*)d_in[12];
  const float* fW3 = (const float*)d_in[13];
  const float* fb3 = (const float*)d_in[14];
  const float* Wq  = (const float*)d_in[15];
  const float* bq  = (const float*)d_in[16];
  const float* Wk  = (const float*)d_in[17];
  const float* bk  = (const float*)d_in[18];
  const float* lng = (const float*)d_in[19];
  const float* lnb = (const float*)d_in[20];
  float* ws = (float*)d_ws;
  float* out = (float*)d_out;
  if (ws_size < WS_FLOATS * sizeof(float)) return;  // visible failure, no OOB

  float* V   = ws + OFF_V;
  float* MID = ws + OFF_MID;
  float* FP  = ws + OFF_MID;   // reuse: MID dead after j-loop
  float* Wm  = ws + OFF_W;
  float* Wfm = ws + OFF_WF;
  float* U1K = ws + OFF_U1K;
  float* U2K = ws + OFF_U2K;
  float* U1F = ws + OFF_U1F;
  float* U2F = ws + OFF_U2F;
  float* GP  = ws + OFF_GP;
  float* SP  = ws + OFF_SP;
  float* A   = ws + OFF_A;
  float* RV  = ws + OFF_RV;
  float* LNP = ws + OFF_LNP;
  float* ZU  = ws + OFF_ZU;
  float* W1v = ws + OFF_W1;
  float* CS  = ws + OFF_CS;

  k_pre_u<<<dim3(4), dim3(256), 0, stream>>>(kW1, kb1, fW1, fb1, U1K, U2K, U1F, U2F);
  k_mlp<<<dim3(16, 256), dim3(64, 4), 0, stream>>>(U1K, U2K, kW2, kb2, kW3, kb3, Wm);
  k_mlp<<<dim3(16, 256), dim3(64, 4), 0, stream>>>(U1F, U2F, fW2, fb2, fW3, fb3, Wfm);
  k_colsum_p1<<<dim3(4, 16), dim3(256), 0, stream>>>(Wm, Wfm, CS);
  k_colsum_p2<<<dim3(4), dim3(256), 0, stream>>>(CS, W1v);

  k_redsum<<<dim3(32, 8), dim3(256), 0, stream>>>(xy, LNP);
  k_apply<<<dim3(1024), dim3(256), 0, stream>>>(xy, lng, lnb, LNP, nullptr, V);

  for (int j = 0; j < 2; j++) {
    k_xty<<<dim3(32, 8), dim3(256), 0, stream>>>(V, V, GP, SP);
    k_heads_f<<<dim3(8), dim3(256), 0, stream>>>(GP, SP, Wq + (size_t)j * RH * 4096, bq + j * RH * 64,
                                                 Wk + (size_t)j * RH * 4096, bk + j * RH * 64,
                                                 A, RV, 32, DXDYf * SCALEf);
    k_mid<<<dim3(32, 8), dim3(256), 0, stream>>>(V, A, RV, MID, LNP);
    k_apply<<<dim3(1024), dim3(256), 0, stream>>>(MID, lng + (size_t)(j + 1) * 131072,
                                                  lnb + (size_t)(j + 1) * 131072, LNP, V, V);
  }

  // final block: H = V_u^T xy_d, t = colsum(xy_d)
  k_xty<<<dim3(16, 8), dim3(256), 0, stream>>>(V, xy, GP, SP);
  k_heads_f<<<dim3(8), dim3(256), 0, stream>>>(GP, SP, Wq + (size_t)2 * RH * 4096, bq + 2 * RH * 64,
                                               Wk + (size_t)2 * RH * 4096, bk + 2 * RH * 64,
                                               A, RV, 16, 1.0f);
  k_y<<<dim3(16, 8, 2), dim3(256), 0, stream>>>(V, A, ZU);
  k_final_part<<<dim3(16, 8, 2), dim3(256), 0, stream>>>(Wm, Wfm, ZU, FP);
  k_final_red<<<dim3(512), dim3(256), 0, stream>>>(FP, W1v, RV, out);
}

// Round 3
// 453.044 us; speedup vs baseline: 2.0759x; 1.7815x over previous
//
#include <hip/hip_runtime.h>

namespace {
constexpr int SD = 1024;           // D
constexpr int TD = 2048;           // 2D
constexpr int BATCH = 8;
constexpr int IDIM = 64;
constexpr int RH = 4;
constexpr float EPSc = 1e-5f;
constexpr float DXf = 2.0f / 31.0f;
constexpr float DXDYf = DXf * DXf;
constexpr float SCALEf = 0.125f;
constexpr float CFINAL = DXDYf * DXDYf * SCALEf;

// workspace offsets (in floats); all multiples of 4 -> float4 safe
constexpr size_t OFF_V   = 0;
constexpr size_t OFF_MID = OFF_V   + (size_t)BATCH * TD * IDIM;   // 1048576; reused as FP after loop
constexpr size_t OFF_W   = OFF_MID + (size_t)BATCH * TD * IDIM;
constexpr size_t OFF_WF  = OFF_W   + (size_t)SD * SD;
constexpr size_t OFF_U1K = OFF_WF  + (size_t)SD * SD;
constexpr size_t OFF_U2K = OFF_U1K + SD * 32;
constexpr size_t OFF_U1F = OFF_U2K + SD * 32;
constexpr size_t OFF_U2F = OFF_U1F + SD * 32;
constexpr size_t OFF_GP  = OFF_U2F + SD * 32;                      // 8*32*4096
constexpr size_t OFF_SP  = OFF_GP  + (size_t)BATCH * 32 * 4096;    // 8*32*64
constexpr size_t OFF_A   = OFF_SP  + BATCH * 32 * 64;              // (dead this round)
constexpr size_t OFF_RV  = OFF_A   + BATCH * 4096;                 // (dead)
constexpr size_t OFF_LNP = OFF_RV  + BATCH * 64;                   // 8*32*2
constexpr size_t OFF_ZU  = OFF_LNP + BATCH * 32 * 2;               // ZU,ZF contiguous
constexpr size_t OFF_ZF  = OFF_ZU  + (size_t)SD * 512;
constexpr size_t OFF_W1  = OFF_ZF  + (size_t)SD * 512;
constexpr size_t OFF_CS  = OFF_W1  + SD;                           // 16*1024 colsum partials
constexpr size_t WS_FLOATS = OFF_CS + 16 * SD;
// temporal overlays (no growth): G->U1K(+U2K), SV->U1F, PM->GP+524288, RP->SP
} // namespace

__device__ __forceinline__ float leaky(float x) { return x > 0.0f ? x : 0.01f * x; }
__device__ __forceinline__ float gxv(int i) { return -1.0f + (2.0f / 31.0f) * (float)i; }

// ---- edge-MLP layer-1 factorization tables ----
__global__ void k_pre_u(const float* __restrict__ kW1, const float* __restrict__ kb1,
                        const float* __restrict__ fW1, const float* __restrict__ fb1,
                        float* __restrict__ u1k, float* __restrict__ u2k,
                        float* __restrict__ u1f, float* __restrict__ u2f) {
  int n = blockIdx.x * blockDim.x + threadIdx.x;
  if (n >= SD) return;
  float ga = gxv(n >> 5), gb = gxv(n & 31);
  for (int j = 0; j < 32; j++) {
    u1k[n * 32 + j] = ga * kW1[j] + gb * kW1[32 + j] + kb1[j];
    u2k[n * 32 + j] = gb * kW1[64 + j] + ga * kW1[96 + j];
    u1f[n * 32 + j] = ga * fW1[j] + gb * fW1[32 + j] + fb1[j];
    u2f[n * 32 + j] = gb * fW1[64 + j] + ga * fW1[96 + j];
  }
}

// ---- per-edge MLP: h1=leaky(u1[n]+u2[m]); h2=leaky(h1@W2+b2); w=h2@W3+b3 ----
__global__ __launch_bounds__(256) void k_mlp(const float* __restrict__ u1, const float* __restrict__ u2,
                                             const float* __restrict__ W2, const float* __restrict__ b2,
                                             const float* __restrict__ W3, const float* __restrict__ b3,
                                             float* __restrict__ out) {
  __shared__ __align__(16) float sW2[2048];
  __shared__ float sW3[64];
  __shared__ float sb2[64];
  __shared__ float su1[4 * 32];
  __shared__ float su2[64 * 33];  // padded stride 33 -> no bank conflict
  int tx = threadIdx.x;           // m local (0..63)
  int ty = threadIdx.y;           // n local (0..3)
  int t = ty * 64 + tx;
  int mtile = blockIdx.x * 64;
  int ntile = blockIdx.y * 4;
  for (int k = t; k < 2048; k += 256) sW2[k] = W2[k];
  if (t < 64) { sW3[t] = W3[t]; sb2[t] = b2[t]; }
  if (t < 128) su1[t] = u1[ntile * 32 + t];
  for (int k = t; k < 2048; k += 256) su2[(k >> 5) * 33 + (k & 31)] = u2[mtile * 32 + k];
  __syncthreads();

  float h1[32];
#pragma unroll
  for (int j = 0; j < 32; j++) h1[j] = leaky(su1[ty * 32 + j] + su2[tx * 33 + j]);
  float acc[64];
#pragma unroll
  for (int o = 0; o < 64; o++) acc[o] = sb2[o];
#pragma unroll
  for (int j = 0; j < 32; j++) {
    float hv = h1[j];
    const float4* w4 = reinterpret_cast<const float4*>(&sW2[j * 64]);
#pragma unroll
    for (int o4 = 0; o4 < 16; o4++) {
      float4 w = w4[o4];
      acc[o4 * 4 + 0] += hv * w.x; acc[o4 * 4 + 1] += hv * w.y;
      acc[o4 * 4 + 2] += hv * w.z; acc[o4 * 4 + 3] += hv * w.w;
    }
  }
  float wsum = b3[0];
#pragma unroll
  for (int o = 0; o < 64; o++) wsum += leaky(acc[o]) * sW3[o];
  out[(size_t)(ntile + ty) * SD + mtile + tx] = wsum;
}

// ---- colsum stage 1: cs[r][c] = sum over 64 rows of (W+Wf) ----
__global__ __launch_bounds__(256) void k_colsum_p1(const float* __restrict__ W, const float* __restrict__ Wf,
                                                   float* __restrict__ cs) {
  int c = blockIdx.x * 256 + threadIdx.x;
  int n0 = blockIdx.y * 64;
  float s = 0.f;
  for (int r = 0; r < 64; r++) s += W[(size_t)(n0 + r) * SD + c] + Wf[(size_t)(n0 + r) * SD + c];
  cs[blockIdx.y * SD + c] = s;
}

__global__ __launch_bounds__(256) void k_colsum_p2(const float* __restrict__ cs, float* __restrict__ w1) {
  int c = blockIdx.x * 256 + threadIdx.x;
  float s = 0.f;
#pragma unroll
  for (int r = 0; r < 16; r++) s += cs[r * SD + c];
  w1[c] = s;
}

// ---- LN partial sums (per batch, 32 chunks of 4096) ----
__global__ __launch_bounds__(256) void k_redsum(const float* __restrict__ X, float* __restrict__ part) {
  int b = blockIdx.y, c = blockIdx.x, t = threadIdx.x;
  const float4* X4 = reinterpret_cast<const float4*>(X + (size_t)b * 131072 + (size_t)c * 4096);
  float s = 0.f, q = 0.f;
#pragma unroll
  for (int k = 0; k < 4; k++) {
    float4 v = X4[t + k * 256];
    s += v.x + v.y + v.z + v.w;
    q += v.x * v.x + v.y * v.y + v.z * v.z + v.w * v.w;
  }
  for (int off = 32; off; off >>= 1) { s += __shfl_down(s, off); q += __shfl_down(q, off); }
  __shared__ float ss[4], qq[4];
  int lane = t & 63, wid = t >> 6;
  if (lane == 0) { ss[wid] = s; qq[wid] = q; }
  __syncthreads();
  if (t == 0) {
    part[(size_t)(b * 32 + c) * 2] = ss[0] + ss[1] + ss[2] + ss[3];
    part[(size_t)(b * 32 + c) * 2 + 1] = qq[0] + qq[1] + qq[2] + qq[3];
  }
}

// ---- apply LN (stats inline from 32 partials): dst = (src-mean)*invstd*g + b (+ addv) ----
__global__ __launch_bounds__(256) void k_apply(const float* __restrict__ src, const float* __restrict__ g,
                                               const float* __restrict__ bb, const float* __restrict__ lnp,
                                               const float* __restrict__ addv, float* __restrict__ dst) {
  __shared__ float sm[2];
  int i4 = blockIdx.x * 256 + threadIdx.x;  // 0..262143
  int b = i4 >> 15;                          // uniform within block
  if (threadIdx.x == 0) {
    float s = 0.f, q = 0.f;
    for (int c = 0; c < 32; c++) { s += lnp[(size_t)(b * 32 + c) * 2]; q += lnp[(size_t)(b * 32 + c) * 2 + 1]; }
    float mean = s / 131072.0f;
    sm[0] = mean;
    sm[1] = rsqrtf(q / 131072.0f - mean * mean + EPSc);
  }
  __syncthreads();
  float mean = sm[0], is = sm[1];
  int p4 = i4 & 32767;
  float4 v = reinterpret_cast<const float4*>(src)[i4];
  float4 gg = reinterpret_cast<const float4*>(g)[p4];
  float4 bv = reinterpret_cast<const float4*>(bb)[p4];
  float4 r;
  r.x = (v.x - mean) * is * gg.x + bv.x;
  r.y = (v.y - mean) * is * gg.y + bv.y;
  r.z = (v.z - mean) * is * gg.z + bv.z;
  r.w = (v.w - mean) * is * gg.w + bv.w;
  if (addv != nullptr) {
    float4 av = reinterpret_cast<const float4*>(addv)[i4];
    r.x += av.x; r.y += av.y; r.z += av.z; r.w += av.w;
  }
  reinterpret_cast<float4*>(dst)[i4] = r;
}

// ---- chunked X^T Y (64 rows per chunk) + colsum(Y) partials ----
__global__ __launch_bounds__(256) void k_xty(const float* __restrict__ Xb, const float* __restrict__ Yb,
                                             float* __restrict__ Gp, float* __restrict__ sp) {
  int c = blockIdx.x, b = blockIdx.y, t = threadIdx.x;
  int nch = gridDim.x;
  const float4* X4 = reinterpret_cast<const float4*>(Xb + (size_t)b * 131072 + (size_t)c * 4096);
  const float4* Y4 = reinterpret_cast<const float4*>(Yb + (size_t)b * 131072 + (size_t)c * 4096);
  __shared__ __align__(16) float Xs[4096];
  __shared__ __align__(16) float Ys[4096];
#pragma unroll
  for (int k = 0; k < 4; k++) {
    reinterpret_cast<float4*>(Xs)[t + k * 256] = X4[t + k * 256];
    reinterpret_cast<float4*>(Ys)[t + k * 256] = Y4[t + k * 256];
  }
  __syncthreads();
  int p = t >> 2, qb = (t & 3) * 16;
  float4 acc[4] = {};
  for (int k = 0; k < 64; k++) {
    float xv = Xs[k * 64 + p];
    const float4* y = reinterpret_cast<const float4*>(&Ys[k * 64 + qb]);
#pragma unroll
    for (int u = 0; u < 4; u++) {
      float4 yv = y[u];
      acc[u].x += xv * yv.x; acc[u].y += xv * yv.y; acc[u].z += xv * yv.z; acc[u].w += xv * yv.w;
    }
  }
  float* go = Gp + (size_t)(b * nch + c) * 4096 + p * 64 + qb;
#pragma unroll
  for (int u = 0; u < 4; u++) reinterpret_cast<float4*>(go)[u] = acc[u];
  if (t < 64) {
    float ssum = 0.f;
    for (int k = 0; k < 64; k++) ssum += Ys[k * 64 + t];
    sp[(size_t)(b * nch + c) * 64 + t] = ssum;
  }
}

// ---- coalesced partial reduction: G = sum_c Gp[c], sv = sum_c sp[c] ----
__global__ __launch_bounds__(256) void k_gred(const float* __restrict__ Gp, const float* __restrict__ sp,
                                              float* __restrict__ G, float* __restrict__ sv, int nch) {
  int blk = blockIdx.x, b = blockIdx.y, t = threadIdx.x;
  int idx = blk * 256 + t;
  float a = 0.f;
  for (int c = 0; c < nch; c++) a += Gp[(size_t)(b * nch + c) * 4096 + idx];
  G[(size_t)b * 4096 + idx] = a;
  if (blk == 0 && t < 64) {
    float s = 0.f;
    for (int c = 0; c < nch; c++) s += sp[(size_t)(b * nch + c) * 64 + t];
    sv[b * 64 + t] = s;
  }
}

// ---- per (head, batch): M = Wk_i^T G + bk_i(x)s ; Pm_i = Wq_i M ; Rp_i = bq_i^T M ----
__global__ __launch_bounds__(256) void k_heads2(const float* __restrict__ G, const float* __restrict__ sv,
                                                const float* __restrict__ Wq, const float* __restrict__ bq,
                                                const float* __restrict__ Wk, const float* __restrict__ bk,
                                                float* __restrict__ Pm, float* __restrict__ Rp) {
  int i = blockIdx.x, b = blockIdx.y, t = threadIdx.x;
  __shared__ __align__(16) float Gs[4096];
  __shared__ __align__(16) float Ms[4096];
  __shared__ __align__(16) float Wks[4096];
  __shared__ float WqsT[64 * 65];  // transposed + pad-65: conflict-free read WqsT[k*65+c]
  __shared__ float ssv[64];
  __shared__ float bqs[64];
  const float4* G4 = reinterpret_cast<const float4*>(G + (size_t)b * 4096);
#pragma unroll
  for (int k = 0; k < 4; k++) reinterpret_cast<float4*>(Gs)[t + k * 256] = G4[t + k * 256];
  const float* wkb = Wk + (size_t)i * 4096;
  for (int idx = t; idx < 4096; idx += 256) Wks[idx] = wkb[idx];
  const float* wqb = Wq + (size_t)i * 4096;
  for (int idx = t; idx < 4096; idx += 256) {
    int c = idx >> 6, k = idx & 63;
    WqsT[k * 65 + c] = wqb[idx];
  }
  if (t < 64) { ssv[t] = sv[b * 64 + t]; bqs[t] = bq[i * 64 + t]; }
  __syncthreads();

  int kk = t >> 2, qb = (t & 3) * 16;
  // phase 1: M[kk][q] = sum_c Wk[c][kk] G[c][q] + bk[kk]*s[q]
  float bkv = bk[i * 64 + kk];
  float4 acc[4];
#pragma unroll
  for (int u = 0; u < 4; u++) {
    acc[u].x = bkv * ssv[qb + u * 4 + 0];
    acc[u].y = bkv * ssv[qb + u * 4 + 1];
    acc[u].z = bkv * ssv[qb + u * 4 + 2];
    acc[u].w = bkv * ssv[qb + u * 4 + 3];
  }
  for (int c = 0; c < 64; c++) {
    float wv = Wks[c * 64 + kk];
    const float4* gr = reinterpret_cast<const float4*>(&Gs[c * 64 + qb]);
#pragma unroll
    for (int u = 0; u < 4; u++) {
      float4 gv = gr[u];
      acc[u].x += wv * gv.x; acc[u].y += wv * gv.y; acc[u].z += wv * gv.z; acc[u].w += wv * gv.w;
    }
  }
#pragma unroll
  for (int u = 0; u < 4; u++) reinterpret_cast<float4*>(&Ms[kk * 64 + qb])[u] = acc[u];
  __syncthreads();
  // phase 2: P[cc=kk][q] = sum_k Wq[cc][k] M[k][q]
  float4 acc2[4] = {};
  for (int k2 = 0; k2 < 64; k2++) {
    float wv = WqsT[k2 * 65 + kk];
    const float4* mr = reinterpret_cast<const float4*>(&Ms[k2 * 64 + qb]);
#pragma unroll
    for (int u = 0; u < 4; u++) {
      float4 mv = mr[u];
      acc2[u].x += wv * mv.x; acc2[u].y += wv * mv.y; acc2[u].z += wv * mv.z; acc2[u].w += wv * mv.w;
    }
  }
  float* po = Pm + (size_t)(b * RH + i) * 4096 + kk * 64 + qb;
#pragma unroll
  for (int u = 0; u < 4; u++) reinterpret_cast<float4*>(po)[u] = acc2[u];
  if (t < 64) {
    float a = 0.f;
    for (int k2 = 0; k2 < 64; k2++) a += bqs[k2] * Ms[k2 * 64 + t];
    Rp[(b * RH + i) * 64 + t] = a;
  }
}

// ---- mid = V @ (scale*sum_i Pm_i) + 1 (scale*sum_i Rp_i)^T, fused LN partials ----
__global__ __launch_bounds__(256) void k_mid(const float* __restrict__ V, const float* __restrict__ Pm,
                                             const float* __restrict__ Rp, float* __restrict__ mid,
                                             float* __restrict__ lnp, float scale) {
  int blk = blockIdx.x, b = blockIdx.y, t = threadIdx.x;
  __shared__ __align__(16) float As[4096];
  __shared__ float rs[64];
  const float4* P4 = reinterpret_cast<const float4*>(Pm + (size_t)b * RH * 4096);
#pragma unroll
  for (int k = 0; k < 4; k++) {
    int idx = t + k * 256;
    float4 a0 = P4[idx], a1 = P4[idx + 1024], a2 = P4[idx + 2048], a3 = P4[idx + 3072];
    float4 r;
    r.x = scale * (a0.x + a1.x + a2.x + a3.x);
    r.y = scale * (a0.y + a1.y + a2.y + a3.y);
    r.z = scale * (a0.z + a1.z + a2.z + a3.z);
    r.w = scale * (a0.w + a1.w + a2.w + a3.w);
    reinterpret_cast<float4*>(As)[idx] = r;
  }
  if (t < 64) {
    const float* rp = Rp + (size_t)b * RH * 64;
    rs[t] = scale * (rp[t] + rp[t + 64] + rp[t + 128] + rp[t + 192]);
  }
  __syncthreads();
  int row = blk * 64 + (t >> 2), qb = (t & 3) * 16;
  const float* vr = V + (size_t)b * 131072 + (size_t)row * 64;
  float4 acc[4];
#pragma unroll
  for (int u = 0; u < 4; u++) {
    acc[u].x = rs[qb + u * 4 + 0]; acc[u].y = rs[qb + u * 4 + 1];
    acc[u].z = rs[qb + u * 4 + 2]; acc[u].w = rs[qb + u * 4 + 3];
  }
  for (int c = 0; c < 64; c++) {
    float vv = vr[c];
    const float4* ar = reinterpret_cast<const float4*>(&As[c * 64 + qb]);
#pragma unroll
    for (int u = 0; u < 4; u++) {
      float4 av = ar[u];
      acc[u].x += vv * av.x; acc[u].y += vv * av.y; acc[u].z += vv * av.z; acc[u].w += vv * av.w;
    }
  }
  float* mo = mid + (size_t)b * 131072 + (size_t)row * 64 + qb;
#pragma unroll
  for (int u = 0; u < 4; u++) reinterpret_cast<float4*>(mo)[u] = acc[u];
  float s = 0.f, q = 0.f;
#pragma unroll
  for (int u = 0; u < 4; u++) {
    s += acc[u].x + acc[u].y + acc[u].z + acc[u].w;
    q += acc[u].x * acc[u].x + acc[u].y * acc[u].y + acc[u].z * acc[u].z + acc[u].w * acc[u].w;
  }
  for (int off = 32; off; off >>= 1) { s += __shfl_down(s, off); q += __shfl_down(q, off); }
  __shared__ float ss[4], qq[4];
  int lane = t & 63, wid = t >> 6;
  if (lane == 0) { ss[wid] = s; qq[wid] = q; }
  __syncthreads();
  if (t == 0) {
    lnp[(size_t)(b * 32 + blk) * 2] = ss[0] + ss[1] + ss[2] + ss[3];
    lnp[(size_t)(b * 32 + blk) * 2 + 1] = qq[0] + qq[1] + qq[2] + qq[3];
  }
}

// ---- Z[z][m][b*64+q] = sum_c V[b][z*1024+m][c] * (sum_i Pm_i)[c][q] ----
__global__ __launch_bounds__(256) void k_y(const float* __restrict__ V, const float* __restrict__ Pm,
                                           float* __restrict__ Z) {
  int blk = blockIdx.x, b = blockIdx.y, z = blockIdx.z, t = threadIdx.x;
  __shared__ __align__(16) float As[4096];
  const float4* P4 = reinterpret_cast<const float4*>(Pm + (size_t)b * RH * 4096);
#pragma unroll
  for (int k = 0; k < 4; k++) {
    int idx = t + k * 256;
    float4 a0 = P4[idx], a1 = P4[idx + 1024], a2 = P4[idx + 2048], a3 = P4[idx + 3072];
    float4 r;
    r.x = a0.x + a1.x + a2.x + a3.x;
    r.y = a0.y + a1.y + a2.y + a3.y;
    r.z = a0.z + a1.z + a2.z + a3.z;
    r.w = a0.w + a1.w + a2.w + a3.w;
    reinterpret_cast<float4*>(As)[idx] = r;
  }
  __syncthreads();
  int m = blk * 64 + (t >> 2), qb = (t & 3) * 16;
  const float* vr = V + (size_t)b * 131072 + (size_t)(z * 1024 + m) * 64;
  float4 acc[4] = {};
  for (int c = 0; c < 64; c++) {
    float vv = vr[c];
    const float4* ar = reinterpret_cast<const float4*>(&As[c * 64 + qb]);
#pragma unroll
    for (int u = 0; u < 4; u++) {
      float4 av = ar[u];
      acc[u].x += vv * av.x; acc[u].y += vv * av.y; acc[u].z += vv * av.z; acc[u].w += vv * av.w;
    }
  }
  float* zo = Z + (size_t)z * 524288 + (size_t)m * 512 + b * 64 + qb;
#pragma unroll
  for (int u = 0; u < 4; u++) reinterpret_cast<float4*>(zo)[u] = acc[u];
}

// ---- final GEMM partial: FP[h][b][n][i] = sum_m Wh[m][n] * Zh[m][b*64+i] ----
__global__ __launch_bounds__(256) void k_final_part(const float* __restrict__ W, const float* __restrict__ Wf,
                                                    const float* __restrict__ Z, float* __restrict__ FP) {
  int tn = blockIdx.x, b = blockIdx.y, h = blockIdx.z, t = threadIdx.x;
  int ntile = tn * 64;
  const float4* Wp = reinterpret_cast<const float4*>(h ? Wf : W);
  const float4* Zp = reinterpret_cast<const float4*>(Z + (size_t)h * 524288);
  __shared__ __align__(16) float Ws[4096];
  __shared__ __align__(16) float Zs[4096];
  int ip = t & 63, wid = t >> 6;
  float acc[16] = {};
  for (int mt = 0; mt < 16; mt++) {
    __syncthreads();
#pragma unroll
    for (int k = 0; k < 4; k++) {
      int f4 = t + k * 256;
      int ml = f4 >> 4, nl4 = f4 & 15;
      reinterpret_cast<float4*>(Ws)[f4] = Wp[(size_t)(mt * 64 + ml) * 256 + (ntile >> 2) + nl4];
      reinterpret_cast<float4*>(Zs)[f4] = Zp[(size_t)(mt * 64 + ml) * 128 + b * 16 + nl4];
    }
    __syncthreads();
    for (int ml = 0; ml < 64; ml++) {
      float zv = Zs[ml * 64 + ip];
      const float4* wr = reinterpret_cast<const float4*>(&Ws[ml * 64 + wid * 16]);
#pragma unroll
      for (int u = 0; u < 4; u++) {
        float4 wv = wr[u];
        acc[u * 4 + 0] += wv.x * zv; acc[u * 4 + 1] += wv.y * zv;
        acc[u * 4 + 2] += wv.z * zv; acc[u * 4 + 3] += wv.w * zv;
      }
    }
  }
  float* op = FP + (size_t)h * 524288 + (size_t)b * 65536 + (size_t)ntile * 64;
#pragma unroll
  for (int u = 0; u < 16; u++) {
    int nl = wid * 16 + u;
    op[(size_t)nl * 64 + ip] = acc[u];
  }
}

// ---- out = CFINAL * (FP0 + FP1 + w1[n]*(sum_i Rp_i)[b][i']) ----
__global__ __launch_bounds__(256) void k_final_red(const float* __restrict__ FP, const float* __restrict__ w1,
                                                   const float* __restrict__ Rp, float* __restrict__ out) {
  int idx4 = blockIdx.x * 256 + threadIdx.x;  // 0..131071 (float4 over out)
  int i4p = idx4 & 15;
  int n = (idx4 >> 4) & 1023;
  int b = idx4 >> 14;
  float4 a = reinterpret_cast<const float4*>(FP)[idx4];
  float4 c = reinterpret_cast<const float4*>(FP)[idx4 + 131072];
  const float4* R4 = reinterpret_cast<const float4*>(Rp + (size_t)b * RH * 64);
  float4 d0 = R4[i4p], d1 = R4[i4p + 16], d2 = R4[i4p + 32], d3 = R4[i4p + 48];
  float4 d;
  d.x = d0.x + d1.x + d2.x + d3.x;
  d.y = d0.y + d1.y + d2.y + d3.y;
  d.z = d0.z + d1.z + d2.z + d3.z;
  d.w = d0.w + d1.w + d2.w + d3.w;
  float wv = w1[n];
  float4 r;
  r.x = CFINAL * (a.x + c.x + wv * d.x);
  r.y = CFINAL * (a.y + c.y + wv * d.y);
  r.z = CFINAL * (a.z + c.z + wv * d.z);
  r.w = CFINAL * (a.w + c.w + wv * d.w);
  reinterpret_cast<float4*>(out)[idx4] = r;
}

extern "C" void kernel_launch(void* const* d_in, const int* in_sizes, int n_in,
                              void* d_out, int out_size, void* d_ws, size_t ws_size,
                              hipStream_t stream) {
  (void)in_sizes; (void)n_in; (void)out_size;
  const float* xy  = (const float*)d_in[1];
  const float* kW1 = (const float*)d_in[3];
  const float* kb1 = (const float*)d_in[4];
  const float* kW2 = (const float*)d_in[5];
  const float* kb2 = (const float*)d_in[6];
  const float* kW3 = (const float*)d_in[7];
  const float* kb3 = (const float*)d_in[8];
  const float* fW1 = (const float*)d_in[9];
  const float* fb1 = (const float*)d_in[10];
  const float* fW2 = (const float*)d_in[11];
  const float* fb2 = (const float*)d_in[12];
  const float* fW3 = (const float*)d_in[13];
  const float* fb3 = (const float*)d_in[14];
  const float* Wq  = (const float*)d_in[15];
  const float* bq  = (const float*)d_in[16];
  const float* Wk  = (const float*)d_in[17];
  const float* bk  = (const float*)d_in[18];
  const float* lng = (const float*)d_in[19];
  const float* lnb = (const float*)d_in[20];
  float* ws = (float*)d_ws;
  float* out = (float*)d_out;
  if (ws_size < WS_FLOATS * sizeof(float)) return;  // visible failure, no OOB

  float* V   = ws + OFF_V;
  float* MID = ws + OFF_MID;
  float* FP  = ws + OFF_MID;            // reuse: MID dead after j-loop
  float* Wm  = ws + OFF_W;
  float* Wfm = ws + OFF_WF;
  float* U1K = ws + OFF_U1K;
  float* U2K = ws + OFF_U2K;
  float* U1F = ws + OFF_U1F;
  float* U2F = ws + OFF_U2F;
  float* GP  = ws + OFF_GP;
  float* SP  = ws + OFF_SP;
  float* LNP = ws + OFF_LNP;
  float* ZU  = ws + OFF_ZU;
  float* W1v = ws + OFF_W1;
  float* CS  = ws + OFF_CS;
  // overlays (temporally disjoint with original owners)
  float* G   = ws + OFF_U1K;            // 32768 (U1K+U2K; U tables dead after k_mlp)
  float* SV  = ws + OFF_U1F;            // 512
  float* PM  = ws + OFF_GP + 524288;    // 131072 (upper half of GP; GP dead after k_gred)
  float* RP  = ws + OFF_SP;             // 2048  (SP dead after k_gred)

  k_pre_u<<<dim3(4), dim3(256), 0, stream>>>(kW1, kb1, fW1, fb1, U1K, U2K, U1F, U2F);
  k_mlp<<<dim3(16, 256), dim3(64, 4), 0, stream>>>(U1K, U2K, kW2, kb2, kW3, kb3, Wm);
  k_mlp<<<dim3(16, 256), dim3(64, 4), 0, stream>>>(U1F, U2F, fW2, fb2, fW3, fb3, Wfm);
  k_colsum_p1<<<dim3(4, 16), dim3(256), 0, stream>>>(Wm, Wfm, CS);
  k_colsum_p2<<<dim3(4), dim3(256), 0, stream>>>(CS, W1v);

  k_redsum<<<dim3(32, 8), dim3(256), 0, stream>>>(xy, LNP);
  k_apply<<<dim3(1024), dim3(256), 0, stream>>>(xy, lng, lnb, LNP, nullptr, V);

  for (int j = 0; j < 2; j++) {
    k_xty<<<dim3(32, 8), dim3(256), 0, stream>>>(V, V, GP, SP);
    k_gred<<<dim3(16, 8), dim3(256), 0, stream>>>(GP, SP, G, SV, 32);
    k_heads2<<<dim3(RH, 8), dim3(256), 0, stream>>>(G, SV, Wq + (size_t)j * RH * 4096, bq + j * RH * 64,
                                                    Wk + (size_t)j * RH * 4096, bk + j * RH * 64, PM, RP);
    k_mid<<<dim3(32, 8), dim3(256), 0, stream>>>(V, PM, RP, MID, LNP, DXDYf * SCALEf);
    k_apply<<<dim3(1024), dim3(256), 0, stream>>>(MID, lng + (size_t)(j + 1) * 131072,
                                                  lnb + (size_t)(j + 1) * 131072, LNP, V, V);
  }

  // final block: H = V_u^T xy_d, t = colsum(xy_d)
  k_xty<<<dim3(16, 8), dim3(256), 0, stream>>>(V, xy, GP, SP);
  k_gred<<<dim3(16, 8), dim3(256), 0, stream>>>(GP, SP, G, SV, 16);
  k_heads2<<<dim3(RH, 8), dim3(256), 0, stream>>>(G, SV, Wq + (size_t)2 * RH * 4096, bq + 2 * RH * 64,
                                                  Wk + (size_t)2 * RH * 4096, bk + 2 * RH * 64, PM, RP);
  k_y<<<dim3(16, 8, 2), dim3(256), 0, stream>>>(V, PM, ZU);
  k_final_part<<<dim3(16, 8, 2), dim3(256), 0, stream>>>(Wm, Wfm, ZU, FP);
  k_final_red<<<dim3(512), dim3(256), 0, stream>>>(FP, W1v, RP, out);
}

// Round 4
// 267.052 us; speedup vs baseline: 3.5216x; 1.6965x over previous
//
#include <hip/hip_runtime.h>

namespace {
constexpr int SD = 1024;           // D
constexpr int TD = 2048;           // 2D
constexpr int BATCH = 8;
constexpr int IDIM = 64;
constexpr int RH = 4;
constexpr float EPSc = 1e-5f;
constexpr float DXf = 2.0f / 31.0f;
constexpr float DXDYf = DXf * DXf;
constexpr float SCALEf = 0.125f;
constexpr float CFINAL = DXDYf * DXDYf * SCALEf;

// workspace offsets (in floats); all multiples of 4 -> float4 safe
constexpr size_t OFF_V   = 0;
constexpr size_t OFF_MID = OFF_V   + (size_t)BATCH * TD * IDIM;   // 1048576; reused as FP after loop
constexpr size_t OFF_W   = OFF_MID + (size_t)BATCH * TD * IDIM;
constexpr size_t OFF_WF  = OFF_W   + (size_t)SD * SD;
constexpr size_t OFF_U1K = OFF_WF  + (size_t)SD * SD;
constexpr size_t OFF_U2K = OFF_U1K + SD * 32;
constexpr size_t OFF_U1F = OFF_U2K + SD * 32;
constexpr size_t OFF_U2F = OFF_U1F + SD * 32;
constexpr size_t OFF_GP  = OFF_U2F + SD * 32;                      // 8*32*4096
constexpr size_t OFF_SP  = OFF_GP  + (size_t)BATCH * 32 * 4096;    // 8*32*64
constexpr size_t OFF_A   = OFF_SP  + BATCH * 32 * 64;              // (dead)
constexpr size_t OFF_RV  = OFF_A   + BATCH * 4096;                 // (dead)
constexpr size_t OFF_LNP = OFF_RV  + BATCH * 64;                   // 8*32*2
constexpr size_t OFF_ZU  = OFF_LNP + BATCH * 32 * 2;               // ZU,ZF contiguous
constexpr size_t OFF_ZF  = OFF_ZU  + (size_t)SD * 512;
constexpr size_t OFF_W1  = OFF_ZF  + (size_t)SD * 512;
constexpr size_t OFF_CS  = OFF_W1  + SD;                           // 16*1024 colsum partials
constexpr size_t WS_FLOATS = OFF_CS + 16 * SD;
// temporal overlays (no growth): G->U1K(+U2K), SV->U1F, PM->GP+524288, RP->SP
} // namespace

typedef __bf16 bf16x8 __attribute__((ext_vector_type(8)));
typedef float f32x4 __attribute__((ext_vector_type(4)));

__device__ __forceinline__ float leaky(float x) { return fmaxf(x, 0.01f * x); }
__device__ __forceinline__ float gxv(int i) { return -1.0f + (2.0f / 31.0f) * (float)i; }

// ---- edge-MLP layer-1 factorization tables ----
__global__ void k_pre_u(const float* __restrict__ kW1, const float* __restrict__ kb1,
                        const float* __restrict__ fW1, const float* __restrict__ fb1,
                        float* __restrict__ u1k, float* __restrict__ u2k,
                        float* __restrict__ u1f, float* __restrict__ u2f) {
  int n = blockIdx.x * blockDim.x + threadIdx.x;
  if (n >= SD) return;
  float ga = gxv(n >> 5), gb = gxv(n & 31);
  for (int j = 0; j < 32; j++) {
    u1k[n * 32 + j] = ga * kW1[j] + gb * kW1[32 + j] + kb1[j];
    u2k[n * 32 + j] = gb * kW1[64 + j] + ga * kW1[96 + j];
    u1f[n * 32 + j] = ga * fW1[j] + gb * fW1[32 + j] + fb1[j];
    u2f[n * 32 + j] = gb * fW1[64 + j] + ga * fW1[96 + j];
  }
}

// ---- MFMA edge-MLP: W[n][m] = W3^T leaky( b2 + leaky(u1[n]+u2[m]) @ W2 ) + b3 ----
// block = one n-row (1024 m points); blockIdx.y selects {k-net, f-net}.
// A-fragment computed in registers per lane: row p=lane&15, k=(lane>>4)*8+i.
// B-fragment (W2 bf16) in registers, loaded once. b2 folded into MFMA C-init.
__global__ __launch_bounds__(256) void k_mlp2(
    const float* __restrict__ u1k, const float* __restrict__ u2k,
    const float* __restrict__ kW2, const float* __restrict__ kb2,
    const float* __restrict__ kW3, const float* __restrict__ kb3,
    const float* __restrict__ u1f, const float* __restrict__ u2f,
    const float* __restrict__ fW2, const float* __restrict__ fb2,
    const float* __restrict__ fW3, const float* __restrict__ fb3,
    float* __restrict__ outK, float* __restrict__ outF) {
  const int which = blockIdx.y;
  const float* u1 = which ? u1f : u1k;
  const float* u2 = which ? u2f : u2k;
  const float* W2 = which ? fW2 : kW2;
  const float* b2 = which ? fb2 : kb2;
  const float* W3 = which ? fW3 : kW3;
  const float* b3 = which ? fb3 : kb3;
  float* out = which ? outF : outK;

  const int t = threadIdx.x;
  const int lane = t & 63, wave = t >> 6;
  const int row = lane & 15, grp = lane >> 4;
  const int n = blockIdx.x;

  // W2 fragments: bfrag[tt][i] = bf16(W2[k=grp*8+i][o=tt*16+row])
  bf16x8 bfrag[4];
  float b2v[4], w3v[4];
#pragma unroll
  for (int tt = 0; tt < 4; tt++) {
    int o = tt * 16 + row;
#pragma unroll
    for (int i = 0; i < 8; i++) bfrag[tt][i] = (__bf16)W2[(grp * 8 + i) * 64 + o];
    b2v[tt] = b2[o];
    w3v[tt] = W3[o];
  }
  float u1j[8];
#pragma unroll
  for (int i = 0; i < 8; i++) u1j[i] = u1[n * 32 + grp * 8 + i];
  const float b3v = b3[0];

  for (int chunk = 0; chunk < 4; chunk++) {
#pragma unroll
    for (int st = 0; st < 4; st++) {
      int mbase = chunk * 256 + wave * 64 + st * 16;
      int m = mbase + row;  // this lane's A-row point
      const float4* u2p = reinterpret_cast<const float4*>(u2 + (size_t)m * 32 + grp * 8);
      float4 ua = u2p[0], ub = u2p[1];
      float hv[8] = {ua.x, ua.y, ua.z, ua.w, ub.x, ub.y, ub.z, ub.w};
      bf16x8 afrag;
#pragma unroll
      for (int i = 0; i < 8; i++) {
        float v = leaky(u1j[i] + hv[i]);
        afrag[i] = (__bf16)v;
      }
      f32x4 c[4];
#pragma unroll
      for (int tt = 0; tt < 4; tt++) {
        f32x4 ci = {b2v[tt], b2v[tt], b2v[tt], b2v[tt]};
        c[tt] = __builtin_amdgcn_mfma_f32_16x16x32_bf16(afrag, bfrag[tt], ci, 0, 0, 0);
      }
      float partial[4] = {0.f, 0.f, 0.f, 0.f};
#pragma unroll
      for (int tt = 0; tt < 4; tt++) {
#pragma unroll
        for (int r = 0; r < 4; r++) {
          partial[r] += leaky(c[tt][r]) * w3v[tt];
        }
      }
#pragma unroll
      for (int r = 0; r < 4; r++) {
        partial[r] += __shfl_xor(partial[r], 1, 64);
        partial[r] += __shfl_xor(partial[r], 2, 64);
        partial[r] += __shfl_xor(partial[r], 4, 64);
        partial[r] += __shfl_xor(partial[r], 8, 64);
      }
      if (row == 0) {
        // C rows p = grp*4 + r  -> m = mbase + grp*4 + r, consecutive float4
        float4 res;
        res.x = partial[0] + b3v; res.y = partial[1] + b3v;
        res.z = partial[2] + b3v; res.w = partial[3] + b3v;
        reinterpret_cast<float4*>(out + (size_t)n * SD + mbase + grp * 4)[0] = res;
      }
    }
  }
}

// ---- colsum stage 1: cs[r][c] = sum over 64 rows of (W+Wf) ----
__global__ __launch_bounds__(256) void k_colsum_p1(const float* __restrict__ W, const float* __restrict__ Wf,
                                                   float* __restrict__ cs) {
  int c = blockIdx.x * 256 + threadIdx.x;
  int n0 = blockIdx.y * 64;
  float s = 0.f;
  for (int r = 0; r < 64; r++) s += W[(size_t)(n0 + r) * SD + c] + Wf[(size_t)(n0 + r) * SD + c];
  cs[blockIdx.y * SD + c] = s;
}

__global__ __launch_bounds__(256) void k_colsum_p2(const float* __restrict__ cs, float* __restrict__ w1) {
  int c = blockIdx.x * 256 + threadIdx.x;
  float s = 0.f;
#pragma unroll
  for (int r = 0; r < 16; r++) s += cs[r * SD + c];
  w1[c] = s;
}

// ---- LN partial sums (per batch, 32 chunks of 4096) ----
__global__ __launch_bounds__(256) void k_redsum(const float* __restrict__ X, float* __restrict__ part) {
  int b = blockIdx.y, c = blockIdx.x, t = threadIdx.x;
  const float4* X4 = reinterpret_cast<const float4*>(X + (size_t)b * 131072 + (size_t)c * 4096);
  float s = 0.f, q = 0.f;
#pragma unroll
  for (int k = 0; k < 4; k++) {
    float4 v = X4[t + k * 256];
    s += v.x + v.y + v.z + v.w;
    q += v.x * v.x + v.y * v.y + v.z * v.z + v.w * v.w;
  }
  for (int off = 32; off; off >>= 1) { s += __shfl_down(s, off); q += __shfl_down(q, off); }
  __shared__ float ss[4], qq[4];
  int lane = t & 63, wid = t >> 6;
  if (lane == 0) { ss[wid] = s; qq[wid] = q; }
  __syncthreads();
  if (t == 0) {
    part[(size_t)(b * 32 + c) * 2] = ss[0] + ss[1] + ss[2] + ss[3];
    part[(size_t)(b * 32 + c) * 2 + 1] = qq[0] + qq[1] + qq[2] + qq[3];
  }
}

// ---- apply LN (stats inline from 32 partials): dst = (src-mean)*invstd*g + b (+ addv) ----
__global__ __launch_bounds__(256) void k_apply(const float* __restrict__ src, const float* __restrict__ g,
                                               const float* __restrict__ bb, const float* __restrict__ lnp,
                                               const float* __restrict__ addv, float* __restrict__ dst) {
  __shared__ float sm[2];
  int i4 = blockIdx.x * 256 + threadIdx.x;  // 0..262143
  int b = i4 >> 15;                          // uniform within block
  if (threadIdx.x == 0) {
    float s = 0.f, q = 0.f;
    for (int c = 0; c < 32; c++) { s += lnp[(size_t)(b * 32 + c) * 2]; q += lnp[(size_t)(b * 32 + c) * 2 + 1]; }
    float mean = s / 131072.0f;
    sm[0] = mean;
    sm[1] = rsqrtf(q / 131072.0f - mean * mean + EPSc);
  }
  __syncthreads();
  float mean = sm[0], is = sm[1];
  int p4 = i4 & 32767;
  float4 v = reinterpret_cast<const float4*>(src)[i4];
  float4 gg = reinterpret_cast<const float4*>(g)[p4];
  float4 bv = reinterpret_cast<const float4*>(bb)[p4];
  float4 r;
  r.x = (v.x - mean) * is * gg.x + bv.x;
  r.y = (v.y - mean) * is * gg.y + bv.y;
  r.z = (v.z - mean) * is * gg.z + bv.z;
  r.w = (v.w - mean) * is * gg.w + bv.w;
  if (addv != nullptr) {
    float4 av = reinterpret_cast<const float4*>(addv)[i4];
    r.x += av.x; r.y += av.y; r.z += av.z; r.w += av.w;
  }
  reinterpret_cast<float4*>(dst)[i4] = r;
}

// ---- chunked X^T Y (64 rows per chunk) + colsum(Y) partials ----
__global__ __launch_bounds__(256) void k_xty(const float* __restrict__ Xb, const float* __restrict__ Yb,
                                             float* __restrict__ Gp, float* __restrict__ sp) {
  int c = blockIdx.x, b = blockIdx.y, t = threadIdx.x;
  int nch = gridDim.x;
  const float4* X4 = reinterpret_cast<const float4*>(Xb + (size_t)b * 131072 + (size_t)c * 4096);
  const float4* Y4 = reinterpret_cast<const float4*>(Yb + (size_t)b * 131072 + (size_t)c * 4096);
  __shared__ __align__(16) float Xs[4096];
  __shared__ __align__(16) float Ys[4096];
#pragma unroll
  for (int k = 0; k < 4; k++) {
    reinterpret_cast<float4*>(Xs)[t + k * 256] = X4[t + k * 256];
    reinterpret_cast<float4*>(Ys)[t + k * 256] = Y4[t + k * 256];
  }
  __syncthreads();
  int p = t >> 2, qb = (t & 3) * 16;
  float4 acc[4] = {};
  for (int k = 0; k < 64; k++) {
    float xv = Xs[k * 64 + p];
    const float4* y = reinterpret_cast<const float4*>(&Ys[k * 64 + qb]);
#pragma unroll
    for (int u = 0; u < 4; u++) {
      float4 yv = y[u];
      acc[u].x += xv * yv.x; acc[u].y += xv * yv.y; acc[u].z += xv * yv.z; acc[u].w += xv * yv.w;
    }
  }
  float* go = Gp + (size_t)(b * nch + c) * 4096 + p * 64 + qb;
#pragma unroll
  for (int u = 0; u < 4; u++) reinterpret_cast<float4*>(go)[u] = acc[u];
  if (t < 64) {
    float ssum = 0.f;
    for (int k = 0; k < 64; k++) ssum += Ys[k * 64 + t];
    sp[(size_t)(b * nch + c) * 64 + t] = ssum;
  }
}

// ---- coalesced partial reduction: G = sum_c Gp[c], sv = sum_c sp[c] ----
__global__ __launch_bounds__(256) void k_gred(const float* __restrict__ Gp, const float* __restrict__ sp,
                                              float* __restrict__ G, float* __restrict__ sv, int nch) {
  int blk = blockIdx.x, b = blockIdx.y, t = threadIdx.x;
  int idx = blk * 256 + t;
  float a = 0.f;
  for (int c = 0; c < nch; c++) a += Gp[(size_t)(b * nch + c) * 4096 + idx];
  G[(size_t)b * 4096 + idx] = a;
  if (blk == 0 && t < 64) {
    float s = 0.f;
    for (int c = 0; c < nch; c++) s += sp[(size_t)(b * nch + c) * 64 + t];
    sv[b * 64 + t] = s;
  }
}

// ---- per (head, batch): M = Wk_i^T G + bk_i(x)s ; Pm_i = Wq_i M ; Rp_i = bq_i^T M ----
__global__ __launch_bounds__(256) void k_heads2(const float* __restrict__ G, const float* __restrict__ sv,
                                                const float* __restrict__ Wq, const float* __restrict__ bq,
                                                const float* __restrict__ Wk, const float* __restrict__ bk,
                                                float* __restrict__ Pm, float* __restrict__ Rp) {
  int i = blockIdx.x, b = blockIdx.y, t = threadIdx.x;
  __shared__ __align__(16) float Gs[4096];
  __shared__ __align__(16) float Ms[4096];
  __shared__ __align__(16) float Wks[4096];
  __shared__ float WqsT[64 * 65];  // transposed + pad-65: conflict-free read WqsT[k*65+c]
  __shared__ float ssv[64];
  __shared__ float bqs[64];
  const float4* G4 = reinterpret_cast<const float4*>(G + (size_t)b * 4096);
#pragma unroll
  for (int k = 0; k < 4; k++) reinterpret_cast<float4*>(Gs)[t + k * 256] = G4[t + k * 256];
  const float* wkb = Wk + (size_t)i * 4096;
  for (int idx = t; idx < 4096; idx += 256) Wks[idx] = wkb[idx];
  const float* wqb = Wq + (size_t)i * 4096;
  for (int idx = t; idx < 4096; idx += 256) {
    int c = idx >> 6, k = idx & 63;
    WqsT[k * 65 + c] = wqb[idx];
  }
  if (t < 64) { ssv[t] = sv[b * 64 + t]; bqs[t] = bq[i * 64 + t]; }
  __syncthreads();

  int kk = t >> 2, qb = (t & 3) * 16;
  // phase 1: M[kk][q] = sum_c Wk[c][kk] G[c][q] + bk[kk]*s[q]
  float bkv = bk[i * 64 + kk];
  float4 acc[4];
#pragma unroll
  for (int u = 0; u < 4; u++) {
    acc[u].x = bkv * ssv[qb + u * 4 + 0];
    acc[u].y = bkv * ssv[qb + u * 4 + 1];
    acc[u].z = bkv * ssv[qb + u * 4 + 2];
    acc[u].w = bkv * ssv[qb + u * 4 + 3];
  }
  for (int c = 0; c < 64; c++) {
    float wv = Wks[c * 64 + kk];
    const float4* gr = reinterpret_cast<const float4*>(&Gs[c * 64 + qb]);
#pragma unroll
    for (int u = 0; u < 4; u++) {
      float4 gv = gr[u];
      acc[u].x += wv * gv.x; acc[u].y += wv * gv.y; acc[u].z += wv * gv.z; acc[u].w += wv * gv.w;
    }
  }
#pragma unroll
  for (int u = 0; u < 4; u++) reinterpret_cast<float4*>(&Ms[kk * 64 + qb])[u] = acc[u];
  __syncthreads();
  // phase 2: P[cc=kk][q] = sum_k Wq[cc][k] M[k][q]
  float4 acc2[4] = {};
  for (int k2 = 0; k2 < 64; k2++) {
    float wv = WqsT[k2 * 65 + kk];
    const float4* mr = reinterpret_cast<const float4*>(&Ms[k2 * 64 + qb]);
#pragma unroll
    for (int u = 0; u < 4; u++) {
      float4 mv = mr[u];
      acc2[u].x += wv * mv.x; acc2[u].y += wv * mv.y; acc2[u].z += wv * mv.z; acc2[u].w += wv * mv.w;
    }
  }
  float* po = Pm + (size_t)(b * RH + i) * 4096 + kk * 64 + qb;
#pragma unroll
  for (int u = 0; u < 4; u++) reinterpret_cast<float4*>(po)[u] = acc2[u];
  if (t < 64) {
    float a = 0.f;
    for (int k2 = 0; k2 < 64; k2++) a += bqs[k2] * Ms[k2 * 64 + t];
    Rp[(b * RH + i) * 64 + t] = a;
  }
}

// ---- mid = V @ (scale*sum_i Pm_i) + 1 (scale*sum_i Rp_i)^T, fused LN partials ----
__global__ __launch_bounds__(256) void k_mid(const float* __restrict__ V, const float* __restrict__ Pm,
                                             const float* __restrict__ Rp, float* __restrict__ mid,
                                             float* __restrict__ lnp, float scale) {
  int blk = blockIdx.x, b = blockIdx.y, t = threadIdx.x;
  __shared__ __align__(16) float As[4096];
  __shared__ float rs[64];
  const float4* P4 = reinterpret_cast<const float4*>(Pm + (size_t)b * RH * 4096);
#pragma unroll
  for (int k = 0; k < 4; k++) {
    int idx = t + k * 256;
    float4 a0 = P4[idx], a1 = P4[idx + 1024], a2 = P4[idx + 2048], a3 = P4[idx + 3072];
    float4 r;
    r.x = scale * (a0.x + a1.x + a2.x + a3.x);
    r.y = scale * (a0.y + a1.y + a2.y + a3.y);
    r.z = scale * (a0.z + a1.z + a2.z + a3.z);
    r.w = scale * (a0.w + a1.w + a2.w + a3.w);
    reinterpret_cast<float4*>(As)[idx] = r;
  }
  if (t < 64) {
    const float* rp = Rp + (size_t)b * RH * 64;
    rs[t] = scale * (rp[t] + rp[t + 64] + rp[t + 128] + rp[t + 192]);
  }
  __syncthreads();
  int row = blk * 64 + (t >> 2), qb = (t & 3) * 16;
  const float* vr = V + (size_t)b * 131072 + (size_t)row * 64;
  float4 acc[4];
#pragma unroll
  for (int u = 0; u < 4; u++) {
    acc[u].x = rs[qb + u * 4 + 0]; acc[u].y = rs[qb + u * 4 + 1];
    acc[u].z = rs[qb + u * 4 + 2]; acc[u].w = rs[qb + u * 4 + 3];
  }
  for (int c = 0; c < 64; c++) {
    float vv = vr[c];
    const float4* ar = reinterpret_cast<const float4*>(&As[c * 64 + qb]);
#pragma unroll
    for (int u = 0; u < 4; u++) {
      float4 av = ar[u];
      acc[u].x += vv * av.x; acc[u].y += vv * av.y; acc[u].z += vv * av.z; acc[u].w += vv * av.w;
    }
  }
  float* mo = mid + (size_t)b * 131072 + (size_t)row * 64 + qb;
#pragma unroll
  for (int u = 0; u < 4; u++) reinterpret_cast<float4*>(mo)[u] = acc[u];
  float s = 0.f, q = 0.f;
#pragma unroll
  for (int u = 0; u < 4; u++) {
    s += acc[u].x + acc[u].y + acc[u].z + acc[u].w;
    q += acc[u].x * acc[u].x + acc[u].y * acc[u].y + acc[u].z * acc[u].z + acc[u].w * acc[u].w;
  }
  for (int off = 32; off; off >>= 1) { s += __shfl_down(s, off); q += __shfl_down(q, off); }
  __shared__ float ss[4], qq[4];
  int lane = t & 63, wid = t >> 6;
  if (lane == 0) { ss[wid] = s; qq[wid] = q; }
  __syncthreads();
  if (t == 0) {
    lnp[(size_t)(b * 32 + blk) * 2] = ss[0] + ss[1] + ss[2] + ss[3];
    lnp[(size_t)(b * 32 + blk) * 2 + 1] = qq[0] + qq[1] + qq[2] + qq[3];
  }
}

// ---- Z[z][m][b*64+q] = sum_c V[b][z*1024+m][c] * (sum_i Pm_i)[c][q] ----
__global__ __launch_bounds__(256) void k_y(const float* __restrict__ V, const float* __restrict__ Pm,
                                           float* __restrict__ Z) {
  int blk = blockIdx.x, b = blockIdx.y, z = blockIdx.z, t = threadIdx.x;
  __shared__ __align__(16) float As[4096];
  const float4* P4 = reinterpret_cast<const float4*>(Pm + (size_t)b * RH * 4096);
#pragma unroll
  for (int k = 0; k < 4; k++) {
    int idx = t + k * 256;
    float4 a0 = P4[idx], a1 = P4[idx + 1024], a2 = P4[idx + 2048], a3 = P4[idx + 3072];
    float4 r;
    r.x = a0.x + a1.x + a2.x + a3.x;
    r.y = a0.y + a1.y + a2.y + a3.y;
    r.z = a0.z + a1.z + a2.z + a3.z;
    r.w = a0.w + a1.w + a2.w + a3.w;
    reinterpret_cast<float4*>(As)[idx] = r;
  }
  __syncthreads();
  int m = blk * 64 + (t >> 2), qb = (t & 3) * 16;
  const float* vr = V + (size_t)b * 131072 + (size_t)(z * 1024 + m) * 64;
  float4 acc[4] = {};
  for (int c = 0; c < 64; c++) {
    float vv = vr[c];
    const float4* ar = reinterpret_cast<const float4*>(&As[c * 64 + qb]);
#pragma unroll
    for (int u = 0; u < 4; u++) {
      float4 av = ar[u];
      acc[u].x += vv * av.x; acc[u].y += vv * av.y; acc[u].z += vv * av.z; acc[u].w += vv * av.w;
    }
  }
  float* zo = Z + (size_t)z * 524288 + (size_t)m * 512 + b * 64 + qb;
#pragma unroll
  for (int u = 0; u < 4; u++) reinterpret_cast<float4*>(zo)[u] = acc[u];
}

// ---- final GEMM partial: FP[h][b][n][i] = sum_m Wh[m][n] * Zh[m][b*64+i] ----
__global__ __launch_bounds__(256) void k_final_part(const float* __restrict__ W, const float* __restrict__ Wf,
                                                    const float* __restrict__ Z, float* __restrict__ FP) {
  int tn = blockIdx.x, b = blockIdx.y, h = blockIdx.z, t = threadIdx.x;
  int ntile = tn * 64;
  const float4* Wp = reinterpret_cast<const float4*>(h ? Wf : W);
  const float4* Zp = reinterpret_cast<const float4*>(Z + (size_t)h * 524288);
  __shared__ __align__(16) float Ws[4096];
  __shared__ __align__(16) float Zs[4096];
  int ip = t & 63, wid = t >> 6;
  float acc[16] = {};
  for (int mt = 0; mt < 16; mt++) {
    __syncthreads();
#pragma unroll
    for (int k = 0; k < 4; k++) {
      int f4 = t + k * 256;
      int ml = f4 >> 4, nl4 = f4 & 15;
      reinterpret_cast<float4*>(Ws)[f4] = Wp[(size_t)(mt * 64 + ml) * 256 + (ntile >> 2) + nl4];
      reinterpret_cast<float4*>(Zs)[f4] = Zp[(size_t)(mt * 64 + ml) * 128 + b * 16 + nl4];
    }
    __syncthreads();
    for (int ml = 0; ml < 64; ml++) {
      float zv = Zs[ml * 64 + ip];
      const float4* wr = reinterpret_cast<const float4*>(&Ws[ml * 64 + wid * 16]);
#pragma unroll
      for (int u = 0; u < 4; u++) {
        float4 wv = wr[u];
        acc[u * 4 + 0] += wv.x * zv; acc[u * 4 + 1] += wv.y * zv;
        acc[u * 4 + 2] += wv.z * zv; acc[u * 4 + 3] += wv.w * zv;
      }
    }
  }
  float* op = FP + (size_t)h * 524288 + (size_t)b * 65536 + (size_t)ntile * 64;
#pragma unroll
  for (int u = 0; u < 16; u++) {
    int nl = wid * 16 + u;
    op[(size_t)nl * 64 + ip] = acc[u];
  }
}

// ---- out = CFINAL * (FP0 + FP1 + w1[n]*(sum_i Rp_i)[b][i']) ----
__global__ __launch_bounds__(256) void k_final_red(const float* __restrict__ FP, const float* __restrict__ w1,
                                                   const float* __restrict__ Rp, float* __restrict__ out) {
  int idx4 = blockIdx.x * 256 + threadIdx.x;  // 0..131071 (float4 over out)
  int i4p = idx4 & 15;
  int n = (idx4 >> 4) & 1023;
  int b = idx4 >> 14;
  float4 a = reinterpret_cast<const float4*>(FP)[idx4];
  float4 c = reinterpret_cast<const float4*>(FP)[idx4 + 131072];
  const float4* R4 = reinterpret_cast<const float4*>(Rp + (size_t)b * RH * 64);
  float4 d0 = R4[i4p], d1 = R4[i4p + 16], d2 = R4[i4p + 32], d3 = R4[i4p + 48];
  float4 d;
  d.x = d0.x + d1.x + d2.x + d3.x;
  d.y = d0.y + d1.y + d2.y + d3.y;
  d.z = d0.z + d1.z + d2.z + d3.z;
  d.w = d0.w + d1.w + d2.w + d3.w;
  float wv = w1[n];
  float4 r;
  r.x = CFINAL * (a.x + c.x + wv * d.x);
  r.y = CFINAL * (a.y + c.y + wv * d.y);
  r.z = CFINAL * (a.z + c.z + wv * d.z);
  r.w = CFINAL * (a.w + c.w + wv * d.w);
  reinterpret_cast<float4*>(out)[idx4] = r;
}

extern "C" void kernel_launch(void* const* d_in, const int* in_sizes, int n_in,
                              void* d_out, int out_size, void* d_ws, size_t ws_size,
                              hipStream_t stream) {
  (void)in_sizes; (void)n_in; (void)out_size;
  const float* xy  = (const float*)d_in[1];
  const float* kW1 = (const float*)d_in[3];
  const float* kb1 = (const float*)d_in[4];
  const float* kW2 = (const float*)d_in[5];
  const float* kb2 = (const float*)d_in[6];
  const float* kW3 = (const float*)d_in[7];
  const float* kb3 = (const float*)d_in[8];
  const float* fW1 = (const float*)d_in[9];
  const float* fb1 = (const float*)d_in[10];
  const float* fW2 = (const float*)d_in[11];
  const float* fb2 = (const float*)d_in[12];
  const float* fW3 = (const float*)d_in[13];
  const float* fb3 = (const float*)d_in[14];
  const float* Wq  = (const float*)d_in[15];
  const float* bq  = (const float*)d_in[16];
  const float* Wk  = (const float*)d_in[17];
  const float* bk  = (const float*)d_in[18];
  const float* lng = (const float*)d_in[19];
  const float* lnb = (const float*)d_in[20];
  float* ws = (float*)d_ws;
  float* out = (float*)d_out;
  if (ws_size < WS_FLOATS * sizeof(float)) return;  // visible failure, no OOB

  float* V   = ws + OFF_V;
  float* MID = ws + OFF_MID;
  float* FP  = ws + OFF_MID;            // reuse: MID dead after j-loop
  float* Wm  = ws + OFF_W;
  float* Wfm = ws + OFF_WF;
  float* U1K = ws + OFF_U1K;
  float* U2K = ws + OFF_U2K;
  float* U1F = ws + OFF_U1F;
  float* U2F = ws + OFF_U2F;
  float* GP  = ws + OFF_GP;
  float* SP  = ws + OFF_SP;
  float* LNP = ws + OFF_LNP;
  float* ZU  = ws + OFF_ZU;
  float* W1v = ws + OFF_W1;
  float* CS  = ws + OFF_CS;
  // overlays (temporally disjoint with original owners)
  float* G   = ws + OFF_U1K;            // 32768 (U1K+U2K; U tables dead after k_mlp2)
  float* SV  = ws + OFF_U1F;            // 512
  float* PM  = ws + OFF_GP + 524288;    // 131072 (upper half of GP; GP dead after k_gred)
  float* RP  = ws + OFF_SP;             // 2048  (SP dead after k_gred)

  k_pre_u<<<dim3(4), dim3(256), 0, stream>>>(kW1, kb1, fW1, fb1, U1K, U2K, U1F, U2F);
  k_mlp2<<<dim3(1024, 2), dim3(256), 0, stream>>>(U1K, U2K, kW2, kb2, kW3, kb3,
                                                  U1F, U2F, fW2, fb2, fW3, fb3, Wm, Wfm);
  k_colsum_p1<<<dim3(4, 16), dim3(256), 0, stream>>>(Wm, Wfm, CS);
  k_colsum_p2<<<dim3(4), dim3(256), 0, stream>>>(CS, W1v);

  k_redsum<<<dim3(32, 8), dim3(256), 0, stream>>>(xy, LNP);
  k_apply<<<dim3(1024), dim3(256), 0, stream>>>(xy, lng, lnb, LNP, nullptr, V);

  for (int j = 0; j < 2; j++) {
    k_xty<<<dim3(32, 8), dim3(256), 0, stream>>>(V, V, GP, SP);
    k_gred<<<dim3(16, 8), dim3(256), 0, stream>>>(GP, SP, G, SV, 32);
    k_heads2<<<dim3(RH, 8), dim3(256), 0, stream>>>(G, SV, Wq + (size_t)j * RH * 4096, bq + j * RH * 64,
                                                    Wk + (size_t)j * RH * 4096, bk + j * RH * 64, PM, RP);
    k_mid<<<dim3(32, 8), dim3(256), 0, stream>>>(V, PM, RP, MID, LNP, DXDYf * SCALEf);
    k_apply<<<dim3(1024), dim3(256), 0, stream>>>(MID, lng + (size_t)(j + 1) * 131072,
                                                  lnb + (size_t)(j + 1) * 131072, LNP, V, V);
  }

  // final block: H = V_u^T xy_d, t = colsum(xy_d)
  k_xty<<<dim3(16, 8), dim3(256), 0, stream>>>(V, xy, GP, SP);
  k_gred<<<dim3(16, 8), dim3(256), 0, stream>>>(GP, SP, G, SV, 16);
  k_heads2<<<dim3(RH, 8), dim3(256), 0, stream>>>(G, SV, Wq + (size_t)2 * RH * 4096, bq + 2 * RH * 64,
                                                  Wk + (size_t)2 * RH * 4096, bk + 2 * RH * 64, PM, RP);
  k_y<<<dim3(16, 8, 2), dim3(256), 0, stream>>>(V, PM, ZU);
  k_final_part<<<dim3(16, 8, 2), dim3(256), 0, stream>>>(Wm, Wfm, ZU, FP);
  k_final_red<<<dim3(512), dim3(256), 0, stream>>>(FP, W1v, RP, out);
}

// Round 5
// 248.773 us; speedup vs baseline: 3.7804x; 1.0735x over previous
//
#include <hip/hip_runtime.h>

namespace {
constexpr int SD = 1024;           // D
constexpr int TD = 2048;           // 2D
constexpr int BATCH = 8;
constexpr int IDIM = 64;
constexpr int RH = 4;
constexpr float EPSc = 1e-5f;
constexpr float DXf = 2.0f / 31.0f;
constexpr float DXDYf = DXf * DXf;
constexpr float SCALEf = 0.125f;
constexpr float CFINAL = DXDYf * DXDYf * SCALEf;

// workspace offsets (in floats); all multiples of 4 -> float4 safe
constexpr size_t OFF_V   = 0;
constexpr size_t OFF_MID = OFF_V   + (size_t)BATCH * TD * IDIM;   // 1048576; reused as FP0 after loop
constexpr size_t OFF_W   = OFF_MID + (size_t)BATCH * TD * IDIM;
constexpr size_t OFF_WF  = OFF_W   + (size_t)SD * SD;
constexpr size_t OFF_U1K = OFF_WF  + (size_t)SD * SD;
constexpr size_t OFF_U2K = OFF_U1K + SD * 32;
constexpr size_t OFF_U1F = OFF_U2K + SD * 32;
constexpr size_t OFF_U2F = OFF_U1F + SD * 32;
constexpr size_t OFF_GP  = OFF_U2F + SD * 32;                      // 8*32*4096; reused as FP1 at end
constexpr size_t OFF_SP  = OFF_GP  + (size_t)BATCH * 32 * 4096;    // 8*32*64
constexpr size_t OFF_A   = OFF_SP  + BATCH * 32 * 64;              // (dead)
constexpr size_t OFF_RV  = OFF_A   + BATCH * 4096;                 // (dead)
constexpr size_t OFF_LNP = OFF_RV  + BATCH * 64;                   // 8*32*2
constexpr size_t OFF_ZU  = OFF_LNP + BATCH * 32 * 2;               // ZU,ZF contiguous
constexpr size_t OFF_ZF  = OFF_ZU  + (size_t)SD * 512;
constexpr size_t OFF_W1  = OFF_ZF  + (size_t)SD * 512;
constexpr size_t OFF_CS  = OFF_W1  + SD;                           // 16*1024 colsum partials
constexpr size_t WS_FLOATS = OFF_CS + 16 * SD;
// temporal overlays (no growth): G->U1K(+U2K), SV->U1F, PM->GP+524288, RP->SP,
// FP0->MID, FP1->GP (PM dead after k_y; GP dead after k_gred)
} // namespace

typedef __bf16 bf16x8 __attribute__((ext_vector_type(8)));
typedef float f32x4 __attribute__((ext_vector_type(4)));

__device__ __forceinline__ float leaky(float x) { return fmaxf(x, 0.01f * x); }
__device__ __forceinline__ float gxv(int i) { return -1.0f + (2.0f / 31.0f) * (float)i; }

// ---- edge-MLP layer-1 factorization tables ----
__global__ void k_pre_u(const float* __restrict__ kW1, const float* __restrict__ kb1,
                        const float* __restrict__ fW1, const float* __restrict__ fb1,
                        float* __restrict__ u1k, float* __restrict__ u2k,
                        float* __restrict__ u1f, float* __restrict__ u2f) {
  int n = blockIdx.x * blockDim.x + threadIdx.x;
  if (n >= SD) return;
  float ga = gxv(n >> 5), gb = gxv(n & 31);
  for (int j = 0; j < 32; j++) {
    u1k[n * 32 + j] = ga * kW1[j] + gb * kW1[32 + j] + kb1[j];
    u2k[n * 32 + j] = gb * kW1[64 + j] + ga * kW1[96 + j];
    u1f[n * 32 + j] = ga * fW1[j] + gb * fW1[32 + j] + fb1[j];
    u2f[n * 32 + j] = gb * fW1[64 + j] + ga * fW1[96 + j];
  }
}

// ---- MFMA edge-MLP: W[n][m] = W3^T leaky( b2 + leaky(u1[n]+u2[m]) @ W2 ) + b3 ----
__global__ __launch_bounds__(256) void k_mlp2(
    const float* __restrict__ u1k, const float* __restrict__ u2k,
    const float* __restrict__ kW2, const float* __restrict__ kb2,
    const float* __restrict__ kW3, const float* __restrict__ kb3,
    const float* __restrict__ u1f, const float* __restrict__ u2f,
    const float* __restrict__ fW2, const float* __restrict__ fb2,
    const float* __restrict__ fW3, const float* __restrict__ fb3,
    float* __restrict__ outK, float* __restrict__ outF) {
  const int which = blockIdx.y;
  const float* u1 = which ? u1f : u1k;
  const float* u2 = which ? u2f : u2k;
  const float* W2 = which ? fW2 : kW2;
  const float* b2 = which ? fb2 : kb2;
  const float* W3 = which ? fW3 : kW3;
  const float* b3 = which ? fb3 : kb3;
  float* out = which ? outF : outK;

  const int t = threadIdx.x;
  const int lane = t & 63, wave = t >> 6;
  const int row = lane & 15, grp = lane >> 4;
  const int n = blockIdx.x;

  bf16x8 bfrag[4];
  float b2v[4], w3v[4];
#pragma unroll
  for (int tt = 0; tt < 4; tt++) {
    int o = tt * 16 + row;
#pragma unroll
    for (int i = 0; i < 8; i++) bfrag[tt][i] = (__bf16)W2[(grp * 8 + i) * 64 + o];
    b2v[tt] = b2[o];
    w3v[tt] = W3[o];
  }
  float u1j[8];
#pragma unroll
  for (int i = 0; i < 8; i++) u1j[i] = u1[n * 32 + grp * 8 + i];
  const float b3v = b3[0];

  for (int chunk = 0; chunk < 4; chunk++) {
#pragma unroll
    for (int st = 0; st < 4; st++) {
      int mbase = chunk * 256 + wave * 64 + st * 16;
      int m = mbase + row;
      const float4* u2p = reinterpret_cast<const float4*>(u2 + (size_t)m * 32 + grp * 8);
      float4 ua = u2p[0], ub = u2p[1];
      float hv[8] = {ua.x, ua.y, ua.z, ua.w, ub.x, ub.y, ub.z, ub.w};
      bf16x8 afrag;
#pragma unroll
      for (int i = 0; i < 8; i++) {
        float v = leaky(u1j[i] + hv[i]);
        afrag[i] = (__bf16)v;
      }
      f32x4 c[4];
#pragma unroll
      for (int tt = 0; tt < 4; tt++) {
        f32x4 ci = {b2v[tt], b2v[tt], b2v[tt], b2v[tt]};
        c[tt] = __builtin_amdgcn_mfma_f32_16x16x32_bf16(afrag, bfrag[tt], ci, 0, 0, 0);
      }
      float partial[4] = {0.f, 0.f, 0.f, 0.f};
#pragma unroll
      for (int tt = 0; tt < 4; tt++) {
#pragma unroll
        for (int r = 0; r < 4; r++) {
          partial[r] += leaky(c[tt][r]) * w3v[tt];
        }
      }
#pragma unroll
      for (int r = 0; r < 4; r++) {
        partial[r] += __shfl_xor(partial[r], 1, 64);
        partial[r] += __shfl_xor(partial[r], 2, 64);
        partial[r] += __shfl_xor(partial[r], 4, 64);
        partial[r] += __shfl_xor(partial[r], 8, 64);
      }
      if (row == 0) {
        float4 res;
        res.x = partial[0] + b3v; res.y = partial[1] + b3v;
        res.z = partial[2] + b3v; res.w = partial[3] + b3v;
        reinterpret_cast<float4*>(out + (size_t)n * SD + mbase + grp * 4)[0] = res;
      }
    }
  }
}

// ---- colsum stage 1: cs[r][c] = sum over 64 rows of (W+Wf) ----
__global__ __launch_bounds__(256) void k_colsum_p1(const float* __restrict__ W, const float* __restrict__ Wf,
                                                   float* __restrict__ cs) {
  int c = blockIdx.x * 256 + threadIdx.x;
  int n0 = blockIdx.y * 64;
  float s = 0.f;
  for (int r = 0; r < 64; r++) s += W[(size_t)(n0 + r) * SD + c] + Wf[(size_t)(n0 + r) * SD + c];
  cs[blockIdx.y * SD + c] = s;
}

__global__ __launch_bounds__(256) void k_colsum_p2(const float* __restrict__ cs, float* __restrict__ w1) {
  int c = blockIdx.x * 256 + threadIdx.x;
  float s = 0.f;
#pragma unroll
  for (int r = 0; r < 16; r++) s += cs[r * SD + c];
  w1[c] = s;
}

// ---- LN partial sums (per batch, 32 chunks of 4096) ----
__global__ __launch_bounds__(256) void k_redsum(const float* __restrict__ X, float* __restrict__ part) {
  int b = blockIdx.y, c = blockIdx.x, t = threadIdx.x;
  const float4* X4 = reinterpret_cast<const float4*>(X + (size_t)b * 131072 + (size_t)c * 4096);
  float s = 0.f, q = 0.f;
#pragma unroll
  for (int k = 0; k < 4; k++) {
    float4 v = X4[t + k * 256];
    s += v.x + v.y + v.z + v.w;
    q += v.x * v.x + v.y * v.y + v.z * v.z + v.w * v.w;
  }
  for (int off = 32; off; off >>= 1) { s += __shfl_down(s, off); q += __shfl_down(q, off); }
  __shared__ float ss[4], qq[4];
  int lane = t & 63, wid = t >> 6;
  if (lane == 0) { ss[wid] = s; qq[wid] = q; }
  __syncthreads();
  if (t == 0) {
    part[(size_t)(b * 32 + c) * 2] = ss[0] + ss[1] + ss[2] + ss[3];
    part[(size_t)(b * 32 + c) * 2 + 1] = qq[0] + qq[1] + qq[2] + qq[3];
  }
}

// ---- apply LN (stats inline from 32 partials): dst = (src-mean)*invstd*g + b (+ addv) ----
__global__ __launch_bounds__(256) void k_apply(const float* __restrict__ src, const float* __restrict__ g,
                                               const float* __restrict__ bb, const float* __restrict__ lnp,
                                               const float* __restrict__ addv, float* __restrict__ dst) {
  __shared__ float sm[2];
  int i4 = blockIdx.x * 256 + threadIdx.x;  // 0..262143
  int b = i4 >> 15;                          // uniform within block
  if (threadIdx.x == 0) {
    float s = 0.f, q = 0.f;
    for (int c = 0; c < 32; c++) { s += lnp[(size_t)(b * 32 + c) * 2]; q += lnp[(size_t)(b * 32 + c) * 2 + 1]; }
    float mean = s / 131072.0f;
    sm[0] = mean;
    sm[1] = rsqrtf(q / 131072.0f - mean * mean + EPSc);
  }
  __syncthreads();
  float mean = sm[0], is = sm[1];
  int p4 = i4 & 32767;
  float4 v = reinterpret_cast<const float4*>(src)[i4];
  float4 gg = reinterpret_cast<const float4*>(g)[p4];
  float4 bv = reinterpret_cast<const float4*>(bb)[p4];
  float4 r;
  r.x = (v.x - mean) * is * gg.x + bv.x;
  r.y = (v.y - mean) * is * gg.y + bv.y;
  r.z = (v.z - mean) * is * gg.z + bv.z;
  r.w = (v.w - mean) * is * gg.w + bv.w;
  if (addv != nullptr) {
    float4 av = reinterpret_cast<const float4*>(addv)[i4];
    r.x += av.x; r.y += av.y; r.z += av.z; r.w += av.w;
  }
  reinterpret_cast<float4*>(dst)[i4] = r;
}

// ---- chunked X^T Y (64 rows/chunk), q-split over blockIdx.z; + colsum(Y) partials ----
__global__ __launch_bounds__(256) void k_xty(const float* __restrict__ Xb, const float* __restrict__ Yb,
                                             float* __restrict__ Gp, float* __restrict__ sp) {
  int c = blockIdx.x, b = blockIdx.y, zh = blockIdx.z, t = threadIdx.x;
  int nch = gridDim.x;
  const float4* X4 = reinterpret_cast<const float4*>(Xb + (size_t)b * 131072 + (size_t)c * 4096);
  const float4* Y4 = reinterpret_cast<const float4*>(Yb + (size_t)b * 131072 + (size_t)c * 4096);
  __shared__ __align__(16) float Xs[4096];
  __shared__ __align__(16) float Ys[4096];
#pragma unroll
  for (int k = 0; k < 4; k++) {
    reinterpret_cast<float4*>(Xs)[t + k * 256] = X4[t + k * 256];
    reinterpret_cast<float4*>(Ys)[t + k * 256] = Y4[t + k * 256];
  }
  __syncthreads();
  int p = t >> 2, ql = zh * 32 + (t & 3) * 8;
  float4 acc[2] = {};
  for (int k = 0; k < 64; k++) {
    float xv = Xs[k * 64 + p];
    const float4* y = reinterpret_cast<const float4*>(&Ys[k * 64 + ql]);
#pragma unroll
    for (int u = 0; u < 2; u++) {
      float4 yv = y[u];
      acc[u].x += xv * yv.x; acc[u].y += xv * yv.y; acc[u].z += xv * yv.z; acc[u].w += xv * yv.w;
    }
  }
  float* go = Gp + (size_t)(b * nch + c) * 4096 + p * 64 + ql;
#pragma unroll
  for (int u = 0; u < 2; u++) reinterpret_cast<float4*>(go)[u] = acc[u];
  if (zh == 0 && t < 64) {
    float ssum = 0.f;
    for (int k = 0; k < 64; k++) ssum += Ys[k * 64 + t];
    sp[(size_t)(b * nch + c) * 64 + t] = ssum;
  }
}

// ---- coalesced partial reduction: G = sum_c Gp[c], sv = sum_c sp[c] ----
__global__ __launch_bounds__(256) void k_gred(const float* __restrict__ Gp, const float* __restrict__ sp,
                                              float* __restrict__ G, float* __restrict__ sv, int nch) {
  int blk = blockIdx.x, b = blockIdx.y, t = threadIdx.x;
  int idx = blk * 256 + t;
  float a = 0.f;
  for (int c = 0; c < nch; c++) a += Gp[(size_t)(b * nch + c) * 4096 + idx];
  G[(size_t)b * 4096 + idx] = a;
  if (blk == 0 && t < 64) {
    float s = 0.f;
    for (int c = 0; c < nch; c++) s += sp[(size_t)(b * nch + c) * 64 + t];
    sv[b * 64 + t] = s;
  }
}

// ---- per (head, batch): M = Wk_i^T G + bk_i(x)s ; Pm_i = Wq_i M ; Rp_i = bq_i^T M ----
__global__ __launch_bounds__(256) void k_heads2(const float* __restrict__ G, const float* __restrict__ sv,
                                                const float* __restrict__ Wq, const float* __restrict__ bq,
                                                const float* __restrict__ Wk, const float* __restrict__ bk,
                                                float* __restrict__ Pm, float* __restrict__ Rp) {
  int i = blockIdx.x, b = blockIdx.y, t = threadIdx.x;
  __shared__ __align__(16) float Gs[4096];
  __shared__ __align__(16) float Ms[4096];
  __shared__ __align__(16) float Wks[4096];
  __shared__ float WqsT[64 * 65];
  __shared__ float ssv[64];
  __shared__ float bqs[64];
  const float4* G4 = reinterpret_cast<const float4*>(G + (size_t)b * 4096);
#pragma unroll
  for (int k = 0; k < 4; k++) reinterpret_cast<float4*>(Gs)[t + k * 256] = G4[t + k * 256];
  const float* wkb = Wk + (size_t)i * 4096;
  for (int idx = t; idx < 4096; idx += 256) Wks[idx] = wkb[idx];
  const float* wqb = Wq + (size_t)i * 4096;
  for (int idx = t; idx < 4096; idx += 256) {
    int c = idx >> 6, k = idx & 63;
    WqsT[k * 65 + c] = wqb[idx];
  }
  if (t < 64) { ssv[t] = sv[b * 64 + t]; bqs[t] = bq[i * 64 + t]; }
  __syncthreads();

  int kk = t >> 2, qb = (t & 3) * 16;
  float bkv = bk[i * 64 + kk];
  float4 acc[4];
#pragma unroll
  for (int u = 0; u < 4; u++) {
    acc[u].x = bkv * ssv[qb + u * 4 + 0];
    acc[u].y = bkv * ssv[qb + u * 4 + 1];
    acc[u].z = bkv * ssv[qb + u * 4 + 2];
    acc[u].w = bkv * ssv[qb + u * 4 + 3];
  }
  for (int c = 0; c < 64; c++) {
    float wv = Wks[c * 64 + kk];
    const float4* gr = reinterpret_cast<const float4*>(&Gs[c * 64 + qb]);
#pragma unroll
    for (int u = 0; u < 4; u++) {
      float4 gv = gr[u];
      acc[u].x += wv * gv.x; acc[u].y += wv * gv.y; acc[u].z += wv * gv.z; acc[u].w += wv * gv.w;
    }
  }
#pragma unroll
  for (int u = 0; u < 4; u++) reinterpret_cast<float4*>(&Ms[kk * 64 + qb])[u] = acc[u];
  __syncthreads();
  float4 acc2[4] = {};
  for (int k2 = 0; k2 < 64; k2++) {
    float wv = WqsT[k2 * 65 + kk];
    const float4* mr = reinterpret_cast<const float4*>(&Ms[k2 * 64 + qb]);
#pragma unroll
    for (int u = 0; u < 4; u++) {
      float4 mv = mr[u];
      acc2[u].x += wv * mv.x; acc2[u].y += wv * mv.y; acc2[u].z += wv * mv.z; acc2[u].w += wv * mv.w;
    }
  }
  float* po = Pm + (size_t)(b * RH + i) * 4096 + kk * 64 + qb;
#pragma unroll
  for (int u = 0; u < 4; u++) reinterpret_cast<float4*>(po)[u] = acc2[u];
  if (t < 64) {
    float a = 0.f;
    for (int k2 = 0; k2 < 64; k2++) a += bqs[k2] * Ms[k2 * 64 + t];
    Rp[(b * RH + i) * 64 + t] = a;
  }
}

// ---- mid = V @ (scale*sum_i Pm_i) + 1 (scale*sum_i Rp_i)^T, fused LN partials ----
__global__ __launch_bounds__(256) void k_mid(const float* __restrict__ V, const float* __restrict__ Pm,
                                             const float* __restrict__ Rp, float* __restrict__ mid,
                                             float* __restrict__ lnp, float scale) {
  int blk = blockIdx.x, b = blockIdx.y, t = threadIdx.x;
  __shared__ __align__(16) float As[4096];
  __shared__ float rs[64];
  const float4* P4 = reinterpret_cast<const float4*>(Pm + (size_t)b * RH * 4096);
#pragma unroll
  for (int k = 0; k < 4; k++) {
    int idx = t + k * 256;
    float4 a0 = P4[idx], a1 = P4[idx + 1024], a2 = P4[idx + 2048], a3 = P4[idx + 3072];
    float4 r;
    r.x = scale * (a0.x + a1.x + a2.x + a3.x);
    r.y = scale * (a0.y + a1.y + a2.y + a3.y);
    r.z = scale * (a0.z + a1.z + a2.z + a3.z);
    r.w = scale * (a0.w + a1.w + a2.w + a3.w);
    reinterpret_cast<float4*>(As)[idx] = r;
  }
  if (t < 64) {
    const float* rp = Rp + (size_t)b * RH * 64;
    rs[t] = scale * (rp[t] + rp[t + 64] + rp[t + 128] + rp[t + 192]);
  }
  __syncthreads();
  int row = blk * 64 + (t >> 2), qb = (t & 3) * 16;
  const float* vr = V + (size_t)b * 131072 + (size_t)row * 64;
  float4 acc[4];
#pragma unroll
  for (int u = 0; u < 4; u++) {
    acc[u].x = rs[qb + u * 4 + 0]; acc[u].y = rs[qb + u * 4 + 1];
    acc[u].z = rs[qb + u * 4 + 2]; acc[u].w = rs[qb + u * 4 + 3];
  }
  for (int c = 0; c < 64; c++) {
    float vv = vr[c];
    const float4* ar = reinterpret_cast<const float4*>(&As[c * 64 + qb]);
#pragma unroll
    for (int u = 0; u < 4; u++) {
      float4 av = ar[u];
      acc[u].x += vv * av.x; acc[u].y += vv * av.y; acc[u].z += vv * av.z; acc[u].w += vv * av.w;
    }
  }
  float* mo = mid + (size_t)b * 131072 + (size_t)row * 64 + qb;
#pragma unroll
  for (int u = 0; u < 4; u++) reinterpret_cast<float4*>(mo)[u] = acc[u];
  float s = 0.f, q = 0.f;
#pragma unroll
  for (int u = 0; u < 4; u++) {
    s += acc[u].x + acc[u].y + acc[u].z + acc[u].w;
    q += acc[u].x * acc[u].x + acc[u].y * acc[u].y + acc[u].z * acc[u].z + acc[u].w * acc[u].w;
  }
  for (int off = 32; off; off >>= 1) { s += __shfl_down(s, off); q += __shfl_down(q, off); }
  __shared__ float ss[4], qq[4];
  int lane = t & 63, wid = t >> 6;
  if (lane == 0) { ss[wid] = s; qq[wid] = q; }
  __syncthreads();
  if (t == 0) {
    lnp[(size_t)(b * 32 + blk) * 2] = ss[0] + ss[1] + ss[2] + ss[3];
    lnp[(size_t)(b * 32 + blk) * 2 + 1] = qq[0] + qq[1] + qq[2] + qq[3];
  }
}

// ---- Z[z][m][b*64+q] = sum_c V[b][z*1024+m][c] * (sum_i Pm_i)[c][q], 32 m-rows/block ----
__global__ __launch_bounds__(256) void k_y(const float* __restrict__ V, const float* __restrict__ Pm,
                                           float* __restrict__ Z) {
  int blk = blockIdx.x, b = blockIdx.y, z = blockIdx.z, t = threadIdx.x;
  __shared__ __align__(16) float As[4096];
  const float4* P4 = reinterpret_cast<const float4*>(Pm + (size_t)b * RH * 4096);
#pragma unroll
  for (int k = 0; k < 4; k++) {
    int idx = t + k * 256;
    float4 a0 = P4[idx], a1 = P4[idx + 1024], a2 = P4[idx + 2048], a3 = P4[idx + 3072];
    float4 r;
    r.x = a0.x + a1.x + a2.x + a3.x;
    r.y = a0.y + a1.y + a2.y + a3.y;
    r.z = a0.z + a1.z + a2.z + a3.z;
    r.w = a0.w + a1.w + a2.w + a3.w;
    reinterpret_cast<float4*>(As)[idx] = r;
  }
  __syncthreads();
  int m = blk * 32 + (t >> 3), qb = (t & 7) * 8;
  const float* vr = V + (size_t)b * 131072 + (size_t)(z * 1024 + m) * 64;
  float4 acc[2] = {};
  for (int c = 0; c < 64; c++) {
    float vv = vr[c];
    const float4* ar = reinterpret_cast<const float4*>(&As[c * 64 + qb]);
#pragma unroll
    for (int u = 0; u < 2; u++) {
      float4 av = ar[u];
      acc[u].x += vv * av.x; acc[u].y += vv * av.y; acc[u].z += vv * av.z; acc[u].w += vv * av.w;
    }
  }
  float* zo = Z + (size_t)z * 524288 + (size_t)m * 512 + b * 64 + qb;
#pragma unroll
  for (int u = 0; u < 2; u++) reinterpret_cast<float4*>(zo)[u] = acc[u];
}

// ---- final GEMM partial, split-K: FP[kz][h][b][n][i] = sum_{m in kz half} Wh[m][n]*Zh[m][b*64+i] ----
__global__ __launch_bounds__(256) void k_final_part(const float* __restrict__ W, const float* __restrict__ Wf,
                                                    const float* __restrict__ Z,
                                                    float* __restrict__ FP0, float* __restrict__ FP1) {
  int tn = blockIdx.x, b = blockIdx.y, t = threadIdx.x;
  int h = blockIdx.z >> 1, kz = blockIdx.z & 1;
  int ntile = tn * 64;
  const float4* Wp = reinterpret_cast<const float4*>(h ? Wf : W);
  const float4* Zp = reinterpret_cast<const float4*>(Z + (size_t)h * 524288);
  __shared__ __align__(16) float Ws[4096];
  __shared__ __align__(16) float Zs[4096];
  int ip = t & 63, wid = t >> 6;
  float acc[16] = {};
  for (int mt = kz * 8; mt < kz * 8 + 8; mt++) {
    __syncthreads();
#pragma unroll
    for (int k = 0; k < 4; k++) {
      int f4 = t + k * 256;
      int ml = f4 >> 4, nl4 = f4 & 15;
      reinterpret_cast<float4*>(Ws)[f4] = Wp[(size_t)(mt * 64 + ml) * 256 + (ntile >> 2) + nl4];
      reinterpret_cast<float4*>(Zs)[f4] = Zp[(size_t)(mt * 64 + ml) * 128 + b * 16 + nl4];
    }
    __syncthreads();
    for (int ml = 0; ml < 64; ml++) {
      float zv = Zs[ml * 64 + ip];
      const float4* wr = reinterpret_cast<const float4*>(&Ws[ml * 64 + wid * 16]);
#pragma unroll
      for (int u = 0; u < 4; u++) {
        float4 wv = wr[u];
        acc[u * 4 + 0] += wv.x * zv; acc[u * 4 + 1] += wv.y * zv;
        acc[u * 4 + 2] += wv.z * zv; acc[u * 4 + 3] += wv.w * zv;
      }
    }
  }
  float* op = (kz ? FP1 : FP0) + (size_t)h * 524288 + (size_t)b * 65536 + (size_t)ntile * 64;
#pragma unroll
  for (int u = 0; u < 16; u++) {
    int nl = wid * 16 + u;
    op[(size_t)nl * 64 + ip] = acc[u];
  }
}

// ---- out = CFINAL * (FP0h0 + FP0h1 + FP1h0 + FP1h1 + w1[n]*(sum_i Rp_i)[b][i']) ----
__global__ __launch_bounds__(256) void k_final_red(const float* __restrict__ FP0, const float* __restrict__ FP1,
                                                   const float* __restrict__ w1,
                                                   const float* __restrict__ Rp, float* __restrict__ out) {
  int idx4 = blockIdx.x * 256 + threadIdx.x;  // 0..131071 (float4 over out)
  int i4p = idx4 & 15;
  int n = (idx4 >> 4) & 1023;
  int b = idx4 >> 14;
  float4 a0 = reinterpret_cast<const float4*>(FP0)[idx4];
  float4 a1 = reinterpret_cast<const float4*>(FP0)[idx4 + 131072];
  float4 c0 = reinterpret_cast<const float4*>(FP1)[idx4];
  float4 c1 = reinterpret_cast<const float4*>(FP1)[idx4 + 131072];
  const float4* R4 = reinterpret_cast<const float4*>(Rp + (size_t)b * RH * 64);
  float4 d0 = R4[i4p], d1 = R4[i4p + 16], d2 = R4[i4p + 32], d3 = R4[i4p + 48];
  float4 d;
  d.x = d0.x + d1.x + d2.x + d3.x;
  d.y = d0.y + d1.y + d2.y + d3.y;
  d.z = d0.z + d1.z + d2.z + d3.z;
  d.w = d0.w + d1.w + d2.w + d3.w;
  float wv = w1[n];
  float4 r;
  r.x = CFINAL * (a0.x + a1.x + c0.x + c1.x + wv * d.x);
  r.y = CFINAL * (a0.y + a1.y + c0.y + c1.y + wv * d.y);
  r.z = CFINAL * (a0.z + a1.z + c0.z + c1.z + wv * d.z);
  r.w = CFINAL * (a0.w + a1.w + c0.w + c1.w + wv * d.w);
  reinterpret_cast<float4*>(out)[idx4] = r;
}

extern "C" void kernel_launch(void* const* d_in, const int* in_sizes, int n_in,
                              void* d_out, int out_size, void* d_ws, size_t ws_size,
                              hipStream_t stream) {
  (void)in_sizes; (void)n_in; (void)out_size;
  const float* xy  = (const float*)d_in[1];
  const float* kW1 = (const float*)d_in[3];
  const float* kb1 = (const float*)d_in[4];
  const float* kW2 = (const float*)d_in[5];
  const float* kb2 = (const float*)d_in[6];
  const float* kW3 = (const float*)d_in[7];
  const float* kb3 = (const float*)d_in[8];
  const float* fW1 = (const float*)d_in[9];
  const float* fb1 = (const float*)d_in[10];
  const float* fW2 = (const float*)d_in[11];
  const float* fb2 = (const float*)d_in[12];
  const float* fW3 = (const float*)d_in[13];
  const float* fb3 = (const float*)d_in[14];
  const float* Wq  = (const float*)d_in[15];
  const float* bq  = (const float*)d_in[16];
  const float* Wk  = (const float*)d_in[17];
  const float* bk  = (const float*)d_in[18];
  const float* lng = (const float*)d_in[19];
  const float* lnb = (const float*)d_in[20];
  float* ws = (float*)d_ws;
  float* out = (float*)d_out;
  if (ws_size < WS_FLOATS * sizeof(float)) return;  // visible failure, no OOB

  float* V   = ws + OFF_V;
  float* MID = ws + OFF_MID;
  float* Wm  = ws + OFF_W;
  float* Wfm = ws + OFF_WF;
  float* U1K = ws + OFF_U1K;
  float* U2K = ws + OFF_U2K;
  float* U1F = ws + OFF_U1F;
  float* U2F = ws + OFF_U2F;
  float* GP  = ws + OFF_GP;
  float* SP  = ws + OFF_SP;
  float* LNP = ws + OFF_LNP;
  float* ZU  = ws + OFF_ZU;
  float* W1v = ws + OFF_W1;
  float* CS  = ws + OFF_CS;
  // overlays (temporally disjoint with original owners)
  float* G   = ws + OFF_U1K;            // 32768 (U1K+U2K; U tables dead after k_mlp2)
  float* SV  = ws + OFF_U1F;            // 512
  float* PM  = ws + OFF_GP + 524288;    // 131072 (upper half of GP; GP dead after k_gred)
  float* RP  = ws + OFF_SP;             // 2048  (SP dead after k_gred)
  float* FP0 = ws + OFF_MID;            // 1048576 (MID dead after j-loop)
  float* FP1 = ws + OFF_GP;             // 1048576 (GP+PM dead after k_y)

  k_pre_u<<<dim3(4), dim3(256), 0, stream>>>(kW1, kb1, fW1, fb1, U1K, U2K, U1F, U2F);
  k_mlp2<<<dim3(1024, 2), dim3(256), 0, stream>>>(U1K, U2K, kW2, kb2, kW3, kb3,
                                                  U1F, U2F, fW2, fb2, fW3, fb3, Wm, Wfm);
  k_colsum_p1<<<dim3(4, 16), dim3(256), 0, stream>>>(Wm, Wfm, CS);
  k_colsum_p2<<<dim3(4), dim3(256), 0, stream>>>(CS, W1v);

  k_redsum<<<dim3(32, 8), dim3(256), 0, stream>>>(xy, LNP);
  k_apply<<<dim3(1024), dim3(256), 0, stream>>>(xy, lng, lnb, LNP, nullptr, V);

  for (int j = 0; j < 2; j++) {
    k_xty<<<dim3(32, 8, 2), dim3(256), 0, stream>>>(V, V, GP, SP);
    k_gred<<<dim3(16, 8), dim3(256), 0, stream>>>(GP, SP, G, SV, 32);
    k_heads2<<<dim3(RH, 8), dim3(256), 0, stream>>>(G, SV, Wq + (size_t)j * RH * 4096, bq + j * RH * 64,
                                                    Wk + (size_t)j * RH * 4096, bk + j * RH * 64, PM, RP);
    k_mid<<<dim3(32, 8), dim3(256), 0, stream>>>(V, PM, RP, MID, LNP, DXDYf * SCALEf);
    k_apply<<<dim3(1024), dim3(256), 0, stream>>>(MID, lng + (size_t)(j + 1) * 131072,
                                                  lnb + (size_t)(j + 1) * 131072, LNP, V, V);
  }

  // final block: H = V_u^T xy_d, t = colsum(xy_d)
  k_xty<<<dim3(16, 8, 2), dim3(256), 0, stream>>>(V, xy, GP, SP);
  k_gred<<<dim3(16, 8), dim3(256), 0, stream>>>(GP, SP, G, SV, 16);
  k_heads2<<<dim3(RH, 8), dim3(256), 0, stream>>>(G, SV, Wq + (size_t)2 * RH * 4096, bq + 2 * RH * 64,
                                                  Wk + (size_t)2 * RH * 4096, bk + 2 * RH * 64, PM, RP);
  k_y<<<dim3(32, 8, 2), dim3(256), 0, stream>>>(V, PM, ZU);
  k_final_part<<<dim3(16, 8, 4), dim3(256), 0, stream>>>(Wm, Wfm, ZU, FP0, FP1);
  k_final_red<<<dim3(512), dim3(256), 0, stream>>>(FP0, FP1, W1v, RP, out);
}

// Round 6
// 231.963 us; speedup vs baseline: 4.0544x; 1.0725x over previous
//
#include <hip/hip_runtime.h>

namespace {
constexpr int SD = 1024;           // D
constexpr int TD = 2048;           // 2D
constexpr int BATCH = 8;
constexpr int IDIM = 64;
constexpr int RH = 4;
constexpr float EPSc = 1e-5f;
constexpr float DXf = 2.0f / 31.0f;
constexpr float DXDYf = DXf * DXf;
constexpr float SCALEf = 0.125f;
constexpr float CFINAL = DXDYf * DXDYf * SCALEf;

// workspace offsets (in floats); all multiples of 4 -> float4 safe
constexpr size_t OFF_V   = 0;
constexpr size_t OFF_MID = OFF_V   + (size_t)BATCH * TD * IDIM;   // 1048576
constexpr size_t OFF_W   = OFF_MID + (size_t)BATCH * TD * IDIM;
constexpr size_t OFF_WF  = OFF_W   + (size_t)SD * SD;
constexpr size_t OFF_U1K = OFF_WF  + (size_t)SD * SD;
constexpr size_t OFF_U2K = OFF_U1K + SD * 32;
constexpr size_t OFF_U1F = OFF_U2K + SD * 32;
constexpr size_t OFF_U2F = OFF_U1F + SD * 32;
constexpr size_t OFF_GP  = OFF_U2F + SD * 32;                      // 8*32*4096
constexpr size_t OFF_SP  = OFF_GP  + (size_t)BATCH * 32 * 4096;    // 8*32*64
constexpr size_t OFF_A   = OFF_SP  + BATCH * 32 * 64;              // (dead)
constexpr size_t OFF_RV  = OFF_A   + BATCH * 4096;                 // (dead)
constexpr size_t OFF_LNP = OFF_RV  + BATCH * 64;                   // 8*32*2
constexpr size_t OFF_ZU  = OFF_LNP + BATCH * 32 * 2;               // ZU,ZF contiguous (2048x512 f32)
constexpr size_t OFF_ZF  = OFF_ZU  + (size_t)SD * 512;
constexpr size_t OFF_W1  = OFF_ZF  + (size_t)SD * 512;
constexpr size_t OFF_CS  = OFF_W1  + SD;                           // 16*1024 colsum partials
constexpr size_t WS_FLOATS = OFF_CS + 16 * SD;
// tail overlays (no growth):
//   G->U1K(+U2K), SV->U1F, PM->GP+524288, RP->SP
//   WbfT (1024x2048 bf16 = 1,048,576 fl) -> V      [V dead after k_y]
//   ZbfT (512x2048 bf16  =   524,288 fl) -> MID    [MID dead after j-loop]
//   P0->GP, P1->GP+524288, P2->MID+524288, P3->ZU  [all dead by k_final_mfma]
} // namespace

typedef __bf16 bf16x8 __attribute__((ext_vector_type(8)));
typedef float f32x4 __attribute__((ext_vector_type(4)));

__device__ __forceinline__ float leaky(float x) { return fmaxf(x, 0.01f * x); }
__device__ __forceinline__ float gxv(int i) { return -1.0f + (2.0f / 31.0f) * (float)i; }

// ---- edge-MLP layer-1 factorization tables ----
__global__ void k_pre_u(const float* __restrict__ kW1, const float* __restrict__ kb1,
                        const float* __restrict__ fW1, const float* __restrict__ fb1,
                        float* __restrict__ u1k, float* __restrict__ u2k,
                        float* __restrict__ u1f, float* __restrict__ u2f) {
  int n = blockIdx.x * blockDim.x + threadIdx.x;
  if (n >= SD) return;
  float ga = gxv(n >> 5), gb = gxv(n & 31);
  for (int j = 0; j < 32; j++) {
    u1k[n * 32 + j] = ga * kW1[j] + gb * kW1[32 + j] + kb1[j];
    u2k[n * 32 + j] = gb * kW1[64 + j] + ga * kW1[96 + j];
    u1f[n * 32 + j] = ga * fW1[j] + gb * fW1[32 + j] + fb1[j];
    u2f[n * 32 + j] = gb * fW1[64 + j] + ga * fW1[96 + j];
  }
}

// ---- MFMA edge-MLP: W[n][m] = W3^T leaky( b2 + leaky(u1[n]+u2[m]) @ W2 ) + b3 ----
__global__ __launch_bounds__(256) void k_mlp2(
    const float* __restrict__ u1k, const float* __restrict__ u2k,
    const float* __restrict__ kW2, const float* __restrict__ kb2,
    const float* __restrict__ kW3, const float* __restrict__ kb3,
    const float* __restrict__ u1f, const float* __restrict__ u2f,
    const float* __restrict__ fW2, const float* __restrict__ fb2,
    const float* __restrict__ fW3, const float* __restrict__ fb3,
    float* __restrict__ outK, float* __restrict__ outF) {
  const int which = blockIdx.y;
  const float* u1 = which ? u1f : u1k;
  const float* u2 = which ? u2f : u2k;
  const float* W2 = which ? fW2 : kW2;
  const float* b2 = which ? fb2 : kb2;
  const float* W3 = which ? fW3 : kW3;
  const float* b3 = which ? fb3 : kb3;
  float* out = which ? outF : outK;

  const int t = threadIdx.x;
  const int lane = t & 63, wave = t >> 6;
  const int row = lane & 15, grp = lane >> 4;
  const int n = blockIdx.x;

  bf16x8 bfrag[4];
  float b2v[4], w3v[4];
#pragma unroll
  for (int tt = 0; tt < 4; tt++) {
    int o = tt * 16 + row;
#pragma unroll
    for (int i = 0; i < 8; i++) bfrag[tt][i] = (__bf16)W2[(grp * 8 + i) * 64 + o];
    b2v[tt] = b2[o];
    w3v[tt] = W3[o];
  }
  float u1j[8];
#pragma unroll
  for (int i = 0; i < 8; i++) u1j[i] = u1[n * 32 + grp * 8 + i];
  const float b3v = b3[0];

  for (int chunk = 0; chunk < 4; chunk++) {
#pragma unroll
    for (int st = 0; st < 4; st++) {
      int mbase = chunk * 256 + wave * 64 + st * 16;
      int m = mbase + row;
      const float4* u2p = reinterpret_cast<const float4*>(u2 + (size_t)m * 32 + grp * 8);
      float4 ua = u2p[0], ub = u2p[1];
      float hv[8] = {ua.x, ua.y, ua.z, ua.w, ub.x, ub.y, ub.z, ub.w};
      bf16x8 afrag;
#pragma unroll
      for (int i = 0; i < 8; i++) {
        float v = leaky(u1j[i] + hv[i]);
        afrag[i] = (__bf16)v;
      }
      f32x4 c[4];
#pragma unroll
      for (int tt = 0; tt < 4; tt++) {
        f32x4 ci = {b2v[tt], b2v[tt], b2v[tt], b2v[tt]};
        c[tt] = __builtin_amdgcn_mfma_f32_16x16x32_bf16(afrag, bfrag[tt], ci, 0, 0, 0);
      }
      float partial[4] = {0.f, 0.f, 0.f, 0.f};
#pragma unroll
      for (int tt = 0; tt < 4; tt++) {
#pragma unroll
        for (int r = 0; r < 4; r++) {
          partial[r] += leaky(c[tt][r]) * w3v[tt];
        }
      }
#pragma unroll
      for (int r = 0; r < 4; r++) {
        partial[r] += __shfl_xor(partial[r], 1, 64);
        partial[r] += __shfl_xor(partial[r], 2, 64);
        partial[r] += __shfl_xor(partial[r], 4, 64);
        partial[r] += __shfl_xor(partial[r], 8, 64);
      }
      if (row == 0) {
        float4 res;
        res.x = partial[0] + b3v; res.y = partial[1] + b3v;
        res.z = partial[2] + b3v; res.w = partial[3] + b3v;
        reinterpret_cast<float4*>(out + (size_t)n * SD + mbase + grp * 4)[0] = res;
      }
    }
  }
}

// ---- colsum stage 1: cs[r][c] = sum over 64 rows of (W+Wf) ----
__global__ __launch_bounds__(256) void k_colsum_p1(const float* __restrict__ W, const float* __restrict__ Wf,
                                                   float* __restrict__ cs) {
  int c = blockIdx.x * 256 + threadIdx.x;
  int n0 = blockIdx.y * 64;
  float s = 0.f;
  for (int r = 0; r < 64; r++) s += W[(size_t)(n0 + r) * SD + c] + Wf[(size_t)(n0 + r) * SD + c];
  cs[blockIdx.y * SD + c] = s;
}

__global__ __launch_bounds__(256) void k_colsum_p2(const float* __restrict__ cs, float* __restrict__ w1) {
  int c = blockIdx.x * 256 + threadIdx.x;
  float s = 0.f;
#pragma unroll
  for (int r = 0; r < 16; r++) s += cs[r * SD + c];
  w1[c] = s;
}

// ---- LN partial sums (per batch, 32 chunks of 4096) ----
__global__ __launch_bounds__(256) void k_redsum(const float* __restrict__ X, float* __restrict__ part) {
  int b = blockIdx.y, c = blockIdx.x, t = threadIdx.x;
  const float4* X4 = reinterpret_cast<const float4*>(X + (size_t)b * 131072 + (size_t)c * 4096);
  float s = 0.f, q = 0.f;
#pragma unroll
  for (int k = 0; k < 4; k++) {
    float4 v = X4[t + k * 256];
    s += v.x + v.y + v.z + v.w;
    q += v.x * v.x + v.y * v.y + v.z * v.z + v.w * v.w;
  }
  for (int off = 32; off; off >>= 1) { s += __shfl_down(s, off); q += __shfl_down(q, off); }
  __shared__ float ss[4], qq[4];
  int lane = t & 63, wid = t >> 6;
  if (lane == 0) { ss[wid] = s; qq[wid] = q; }
  __syncthreads();
  if (t == 0) {
    part[(size_t)(b * 32 + c) * 2] = ss[0] + ss[1] + ss[2] + ss[3];
    part[(size_t)(b * 32 + c) * 2 + 1] = qq[0] + qq[1] + qq[2] + qq[3];
  }
}

// ---- apply LN (stats inline from 32 partials): dst = (src-mean)*invstd*g + b (+ addv) ----
__global__ __launch_bounds__(256) void k_apply(const float* __restrict__ src, const float* __restrict__ g,
                                               const float* __restrict__ bb, const float* __restrict__ lnp,
                                               const float* __restrict__ addv, float* __restrict__ dst) {
  __shared__ float sm[2];
  int i4 = blockIdx.x * 256 + threadIdx.x;  // 0..262143
  int b = i4 >> 15;                          // uniform within block
  if (threadIdx.x == 0) {
    float s = 0.f, q = 0.f;
    for (int c = 0; c < 32; c++) { s += lnp[(size_t)(b * 32 + c) * 2]; q += lnp[(size_t)(b * 32 + c) * 2 + 1]; }
    float mean = s / 131072.0f;
    sm[0] = mean;
    sm[1] = rsqrtf(q / 131072.0f - mean * mean + EPSc);
  }
  __syncthreads();
  float mean = sm[0], is = sm[1];
  int p4 = i4 & 32767;
  float4 v = reinterpret_cast<const float4*>(src)[i4];
  float4 gg = reinterpret_cast<const float4*>(g)[p4];
  float4 bv = reinterpret_cast<const float4*>(bb)[p4];
  float4 r;
  r.x = (v.x - mean) * is * gg.x + bv.x;
  r.y = (v.y - mean) * is * gg.y + bv.y;
  r.z = (v.z - mean) * is * gg.z + bv.z;
  r.w = (v.w - mean) * is * gg.w + bv.w;
  if (addv != nullptr) {
    float4 av = reinterpret_cast<const float4*>(addv)[i4];
    r.x += av.x; r.y += av.y; r.z += av.z; r.w += av.w;
  }
  reinterpret_cast<float4*>(dst)[i4] = r;
}

// ---- chunked X^T Y (64 rows/chunk), q-split over blockIdx.z; + colsum(Y) partials ----
__global__ __launch_bounds__(256) void k_xty(const float* __restrict__ Xb, const float* __restrict__ Yb,
                                             float* __restrict__ Gp, float* __restrict__ sp) {
  int c = blockIdx.x, b = blockIdx.y, zh = blockIdx.z, t = threadIdx.x;
  int nch = gridDim.x;
  const float4* X4 = reinterpret_cast<const float4*>(Xb + (size_t)b * 131072 + (size_t)c * 4096);
  const float4* Y4 = reinterpret_cast<const float4*>(Yb + (size_t)b * 131072 + (size_t)c * 4096);
  __shared__ __align__(16) float Xs[4096];
  __shared__ __align__(16) float Ys[4096];
#pragma unroll
  for (int k = 0; k < 4; k++) {
    reinterpret_cast<float4*>(Xs)[t + k * 256] = X4[t + k * 256];
    reinterpret_cast<float4*>(Ys)[t + k * 256] = Y4[t + k * 256];
  }
  __syncthreads();
  int p = t >> 2, ql = zh * 32 + (t & 3) * 8;
  float4 acc[2] = {};
  for (int k = 0; k < 64; k++) {
    float xv = Xs[k * 64 + p];
    const float4* y = reinterpret_cast<const float4*>(&Ys[k * 64 + ql]);
#pragma unroll
    for (int u = 0; u < 2; u++) {
      float4 yv = y[u];
      acc[u].x += xv * yv.x; acc[u].y += xv * yv.y; acc[u].z += xv * yv.z; acc[u].w += xv * yv.w;
    }
  }
  float* go = Gp + (size_t)(b * nch + c) * 4096 + p * 64 + ql;
#pragma unroll
  for (int u = 0; u < 2; u++) reinterpret_cast<float4*>(go)[u] = acc[u];
  if (zh == 0 && t < 64) {
    float ssum = 0.f;
    for (int k = 0; k < 64; k++) ssum += Ys[k * 64 + t];
    sp[(size_t)(b * nch + c) * 64 + t] = ssum;
  }
}

// ---- coalesced partial reduction: G = sum_c Gp[c], sv = sum_c sp[c] ----
__global__ __launch_bounds__(256) void k_gred(const float* __restrict__ Gp, const float* __restrict__ sp,
                                              float* __restrict__ G, float* __restrict__ sv, int nch) {
  int blk = blockIdx.x, b = blockIdx.y, t = threadIdx.x;
  int idx = blk * 256 + t;
  float a = 0.f;
  for (int c = 0; c < nch; c++) a += Gp[(size_t)(b * nch + c) * 4096 + idx];
  G[(size_t)b * 4096 + idx] = a;
  if (blk == 0 && t < 64) {
    float s = 0.f;
    for (int c = 0; c < nch; c++) s += sp[(size_t)(b * nch + c) * 64 + t];
    sv[b * 64 + t] = s;
  }
}

// ---- per (head, batch): M = Wk_i^T G + bk_i(x)s ; Pm_i = Wq_i M ; Rp_i = bq_i^T M ----
__global__ __launch_bounds__(256) void k_heads2(const float* __restrict__ G, const float* __restrict__ sv,
                                                const float* __restrict__ Wq, const float* __restrict__ bq,
                                                const float* __restrict__ Wk, const float* __restrict__ bk,
                                                float* __restrict__ Pm, float* __restrict__ Rp) {
  int i = blockIdx.x, b = blockIdx.y, t = threadIdx.x;
  __shared__ __align__(16) float Gs[4096];
  __shared__ __align__(16) float Ms[4096];
  __shared__ __align__(16) float Wks[4096];
  __shared__ float WqsT[64 * 65];
  __shared__ float ssv[64];
  __shared__ float bqs[64];
  const float4* G4 = reinterpret_cast<const float4*>(G + (size_t)b * 4096);
#pragma unroll
  for (int k = 0; k < 4; k++) reinterpret_cast<float4*>(Gs)[t + k * 256] = G4[t + k * 256];
  const float* wkb = Wk + (size_t)i * 4096;
  for (int idx = t; idx < 4096; idx += 256) Wks[idx] = wkb[idx];
  const float* wqb = Wq + (size_t)i * 4096;
  for (int idx = t; idx < 4096; idx += 256) {
    int c = idx >> 6, k = idx & 63;
    WqsT[k * 65 + c] = wqb[idx];
  }
  if (t < 64) { ssv[t] = sv[b * 64 + t]; bqs[t] = bq[i * 64 + t]; }
  __syncthreads();

  int kk = t >> 2, qb = (t & 3) * 16;
  float bkv = bk[i * 64 + kk];
  float4 acc[4];
#pragma unroll
  for (int u = 0; u < 4; u++) {
    acc[u].x = bkv * ssv[qb + u * 4 + 0];
    acc[u].y = bkv * ssv[qb + u * 4 + 1];
    acc[u].z = bkv * ssv[qb + u * 4 + 2];
    acc[u].w = bkv * ssv[qb + u * 4 + 3];
  }
  for (int c = 0; c < 64; c++) {
    float wv = Wks[c * 64 + kk];
    const float4* gr = reinterpret_cast<const float4*>(&Gs[c * 64 + qb]);
#pragma unroll
    for (int u = 0; u < 4; u++) {
      float4 gv = gr[u];
      acc[u].x += wv * gv.x; acc[u].y += wv * gv.y; acc[u].z += wv * gv.z; acc[u].w += wv * gv.w;
    }
  }
#pragma unroll
  for (int u = 0; u < 4; u++) reinterpret_cast<float4*>(&Ms[kk * 64 + qb])[u] = acc[u];
  __syncthreads();
  float4 acc2[4] = {};
  for (int k2 = 0; k2 < 64; k2++) {
    float wv = WqsT[k2 * 65 + kk];
    const float4* mr = reinterpret_cast<const float4*>(&Ms[k2 * 64 + qb]);
#pragma unroll
    for (int u = 0; u < 4; u++) {
      float4 mv = mr[u];
      acc2[u].x += wv * mv.x; acc2[u].y += wv * mv.y; acc2[u].z += wv * mv.z; acc2[u].w += wv * mv.w;
    }
  }
  float* po = Pm + (size_t)(b * RH + i) * 4096 + kk * 64 + qb;
#pragma unroll
  for (int u = 0; u < 4; u++) reinterpret_cast<float4*>(po)[u] = acc2[u];
  if (t < 64) {
    float a = 0.f;
    for (int k2 = 0; k2 < 64; k2++) a += bqs[k2] * Ms[k2 * 64 + t];
    Rp[(b * RH + i) * 64 + t] = a;
  }
}

// ---- mid = V @ (scale*sum_i Pm_i) + 1 (scale*sum_i Rp_i)^T, fused LN partials ----
__global__ __launch_bounds__(256) void k_mid(const float* __restrict__ V, const float* __restrict__ Pm,
                                             const float* __restrict__ Rp, float* __restrict__ mid,
                                             float* __restrict__ lnp, float scale) {
  int blk = blockIdx.x, b = blockIdx.y, t = threadIdx.x;
  __shared__ __align__(16) float As[4096];
  __shared__ float rs[64];
  const float4* P4 = reinterpret_cast<const float4*>(Pm + (size_t)b * RH * 4096);
#pragma unroll
  for (int k = 0; k < 4; k++) {
    int idx = t + k * 256;
    float4 a0 = P4[idx], a1 = P4[idx + 1024], a2 = P4[idx + 2048], a3 = P4[idx + 3072];
    float4 r;
    r.x = scale * (a0.x + a1.x + a2.x + a3.x);
    r.y = scale * (a0.y + a1.y + a2.y + a3.y);
    r.z = scale * (a0.z + a1.z + a2.z + a3.z);
    r.w = scale * (a0.w + a1.w + a2.w + a3.w);
    reinterpret_cast<float4*>(As)[idx] = r;
  }
  if (t < 64) {
    const float* rp = Rp + (size_t)b * RH * 64;
    rs[t] = scale * (rp[t] + rp[t + 64] + rp[t + 128] + rp[t + 192]);
  }
  __syncthreads();
  int row = blk * 64 + (t >> 2), qb = (t & 3) * 16;
  const float* vr = V + (size_t)b * 131072 + (size_t)row * 64;
  float4 acc[4];
#pragma unroll
  for (int u = 0; u < 4; u++) {
    acc[u].x = rs[qb + u * 4 + 0]; acc[u].y = rs[qb + u * 4 + 1];
    acc[u].z = rs[qb + u * 4 + 2]; acc[u].w = rs[qb + u * 4 + 3];
  }
  for (int c = 0; c < 64; c++) {
    float vv = vr[c];
    const float4* ar = reinterpret_cast<const float4*>(&As[c * 64 + qb]);
#pragma unroll
    for (int u = 0; u < 4; u++) {
      float4 av = ar[u];
      acc[u].x += vv * av.x; acc[u].y += vv * av.y; acc[u].z += vv * av.z; acc[u].w += vv * av.w;
    }
  }
  float* mo = mid + (size_t)b * 131072 + (size_t)row * 64 + qb;
#pragma unroll
  for (int u = 0; u < 4; u++) reinterpret_cast<float4*>(mo)[u] = acc[u];
  float s = 0.f, q = 0.f;
#pragma unroll
  for (int u = 0; u < 4; u++) {
    s += acc[u].x + acc[u].y + acc[u].z + acc[u].w;
    q += acc[u].x * acc[u].x + acc[u].y * acc[u].y + acc[u].z * acc[u].z + acc[u].w * acc[u].w;
  }
  for (int off = 32; off; off >>= 1) { s += __shfl_down(s, off); q += __shfl_down(q, off); }
  __shared__ float ss[4], qq[4];
  int lane = t & 63, wid = t >> 6;
  if (lane == 0) { ss[wid] = s; qq[wid] = q; }
  __syncthreads();
  if (t == 0) {
    lnp[(size_t)(b * 32 + blk) * 2] = ss[0] + ss[1] + ss[2] + ss[3];
    lnp[(size_t)(b * 32 + blk) * 2 + 1] = qq[0] + qq[1] + qq[2] + qq[3];
  }
}

// ---- Z[z][m][b*64+q] = sum_c V[b][z*1024+m][c] * (sum_i Pm_i)[c][q], 32 m-rows/block ----
__global__ __launch_bounds__(256) void k_y(const float* __restrict__ V, const float* __restrict__ Pm,
                                           float* __restrict__ Z) {
  int blk = blockIdx.x, b = blockIdx.y, z = blockIdx.z, t = threadIdx.x;
  __shared__ __align__(16) float As[4096];
  const float4* P4 = reinterpret_cast<const float4*>(Pm + (size_t)b * RH * 4096);
#pragma unroll
  for (int k = 0; k < 4; k++) {
    int idx = t + k * 256;
    float4 a0 = P4[idx], a1 = P4[idx + 1024], a2 = P4[idx + 2048], a3 = P4[idx + 3072];
    float4 r;
    r.x = a0.x + a1.x + a2.x + a3.x;
    r.y = a0.y + a1.y + a2.y + a3.y;
    r.z = a0.z + a1.z + a2.z + a3.z;
    r.w = a0.w + a1.w + a2.w + a3.w;
    reinterpret_cast<float4*>(As)[idx] = r;
  }
  __syncthreads();
  int m = blk * 32 + (t >> 3), qb = (t & 7) * 8;
  const float* vr = V + (size_t)b * 131072 + (size_t)(z * 1024 + m) * 64;
  float4 acc[2] = {};
  for (int c = 0; c < 64; c++) {
    float vv = vr[c];
    const float4* ar = reinterpret_cast<const float4*>(&As[c * 64 + qb]);
#pragma unroll
    for (int u = 0; u < 2; u++) {
      float4 av = ar[u];
      acc[u].x += vv * av.x; acc[u].y += vv * av.y; acc[u].z += vv * av.z; acc[u].w += vv * av.w;
    }
  }
  float* zo = Z + (size_t)z * 524288 + (size_t)m * 512 + b * 64 + qb;
#pragma unroll
  for (int u = 0; u < 2; u++) reinterpret_cast<float4*>(zo)[u] = acc[u];
}

// ---- transpose + f32->bf16 convert: dst[c][colOff + r] = bf16(src[r][c]) ----
// grid.x = C/64, grid.y = R/64, grid.z selects srcA (colOff 0) / srcB (colOff colOffB).
// dst row stride fixed 2048 (bf16 elems).
__global__ __launch_bounds__(256) void k_cvtT(const float* __restrict__ srcA, const float* __restrict__ srcB,
                                              int srcStride, ushort* __restrict__ dst, int colOffB) {
  __shared__ float T[64][65];
  const float* src = blockIdx.z ? srcB : srcA;
  int colOff = blockIdx.z ? colOffB : 0;
  int t = threadIdx.x;
  int c0 = blockIdx.x * 64, r0 = blockIdx.y * 64;
  int rr = t >> 2, cc = (t & 3) * 16;
  const float4* s4 = reinterpret_cast<const float4*>(src + (size_t)(r0 + rr) * srcStride + c0 + cc);
#pragma unroll
  for (int j = 0; j < 4; j++) {
    float4 v = s4[j];
    T[rr][cc + j * 4 + 0] = v.x; T[rr][cc + j * 4 + 1] = v.y;
    T[rr][cc + j * 4 + 2] = v.z; T[rr][cc + j * 4 + 3] = v.w;
  }
  __syncthreads();
  uint pk[8];
#pragma unroll
  for (int j = 0; j < 8; j++) {
    union { __bf16 b; ushort u; } lo, hi;
    lo.b = (__bf16)T[cc + 2 * j][rr];
    hi.b = (__bf16)T[cc + 2 * j + 1][rr];
    pk[j] = (uint)lo.u | ((uint)hi.u << 16);
  }
  ushort* dp = dst + (size_t)(c0 + rr) * 2048 + colOff + r0 + cc;
  uint4* dp4 = reinterpret_cast<uint4*>(dp);
  dp4[0] = make_uint4(pk[0], pk[1], pk[2], pk[3]);
  dp4[1] = make_uint4(pk[4], pk[5], pk[6], pk[7]);
}

// ---- MFMA final GEMM: P_kz[n][bi] = sum_{K in kz quarter} WT[n][K] * ZT[bi][K] ----
// WT [1024][2048] bf16, ZT [512][2048] bf16; per-lane direct 16B global fragment loads.
__global__ __launch_bounds__(256) void k_final_mfma(const ushort* __restrict__ WT,
                                                    const ushort* __restrict__ ZT,
                                                    float* __restrict__ P0, float* __restrict__ P1,
                                                    float* __restrict__ P2, float* __restrict__ P3) {
  int tn = blockIdx.x, tb = blockIdx.y, kz = blockIdx.z, t = threadIdx.x;
  int lane = t & 63, w = t >> 6;
  int wn = w >> 1, wb = w & 1;
  int r = lane & 15, g = lane >> 4;
  int n_a0 = tn * 64 + wn * 32 + r;
  int bi_b0 = tb * 64 + wb * 32 + r;
  const ushort* wp0 = WT + (size_t)n_a0 * 2048 + kz * 512 + g * 8;
  const ushort* wp1 = wp0 + 16 * 2048;
  const ushort* zp0 = ZT + (size_t)bi_b0 * 2048 + kz * 512 + g * 8;
  const ushort* zp1 = zp0 + 16 * 2048;
  f32x4 a00 = {0.f, 0.f, 0.f, 0.f}, a01 = a00, a10 = a00, a11 = a00;
#pragma unroll 4
  for (int ks = 0; ks < 512; ks += 32) {
    bf16x8 fa0 = *reinterpret_cast<const bf16x8*>(wp0 + ks);
    bf16x8 fa1 = *reinterpret_cast<const bf16x8*>(wp1 + ks);
    bf16x8 fb0 = *reinterpret_cast<const bf16x8*>(zp0 + ks);
    bf16x8 fb1 = *reinterpret_cast<const bf16x8*>(zp1 + ks);
    a00 = __builtin_amdgcn_mfma_f32_16x16x32_bf16(fa0, fb0, a00, 0, 0, 0);
    a01 = __builtin_amdgcn_mfma_f32_16x16x32_bf16(fa0, fb1, a01, 0, 0, 0);
    a10 = __builtin_amdgcn_mfma_f32_16x16x32_bf16(fa1, fb0, a10, 0, 0, 0);
    a11 = __builtin_amdgcn_mfma_f32_16x16x32_bf16(fa1, fb1, a11, 0, 0, 0);
  }
  float* P = kz == 0 ? P0 : kz == 1 ? P1 : kz == 2 ? P2 : P3;
  int nbase = tn * 64 + wn * 32 + g * 4;
  int bibase = tb * 64 + wb * 32 + r;
#pragma unroll
  for (int rr = 0; rr < 4; rr++) {
    P[(size_t)(nbase + rr) * 512 + bibase]           = a00[rr];
    P[(size_t)(nbase + rr) * 512 + bibase + 16]      = a01[rr];
    P[(size_t)(nbase + 16 + rr) * 512 + bibase]      = a10[rr];
    P[(size_t)(nbase + 16 + rr) * 512 + bibase + 16] = a11[rr];
  }
}

// ---- out = CFINAL * (P0+P1+P2+P3 + w1[n]*(sum_i Rp_i)[b][i']) ----
__global__ __launch_bounds__(256) void k_final_red(const float* __restrict__ P0, const float* __restrict__ P1,
                                                   const float* __restrict__ P2, const float* __restrict__ P3,
                                                   const float* __restrict__ w1,
                                                   const float* __restrict__ Rp, float* __restrict__ out) {
  int idx4 = blockIdx.x * 256 + threadIdx.x;  // 0..131071 (float4 over out)
  int i4p = idx4 & 15;
  int n = (idx4 >> 4) & 1023;
  int b = idx4 >> 14;
  int pidx = n * 128 + b * 16 + i4p;           // float4 index into P[1024][512]
  float4 a0 = reinterpret_cast<const float4*>(P0)[pidx];
  float4 a1 = reinterpret_cast<const float4*>(P1)[pidx];
  float4 a2 = reinterpret_cast<const float4*>(P2)[pidx];
  float4 a3 = reinterpret_cast<const float4*>(P3)[pidx];
  const float4* R4 = reinterpret_cast<const float4*>(Rp + (size_t)b * RH * 64);
  float4 d0 = R4[i4p], d1 = R4[i4p + 16], d2 = R4[i4p + 32], d3 = R4[i4p + 48];
  float4 d;
  d.x = d0.x + d1.x + d2.x + d3.x;
  d.y = d0.y + d1.y + d2.y + d3.y;
  d.z = d0.z + d1.z + d2.z + d3.z;
  d.w = d0.w + d1.w + d2.w + d3.w;
  float wv = w1[n];
  float4 r;
  r.x = CFINAL * (a0.x + a1.x + a2.x + a3.x + wv * d.x);
  r.y = CFINAL * (a0.y + a1.y + a2.y + a3.y + wv * d.y);
  r.z = CFINAL * (a0.z + a1.z + a2.z + a3.z + wv * d.z);
  r.w = CFINAL * (a0.w + a1.w + a2.w + a3.w + wv * d.w);
  reinterpret_cast<float4*>(out)[idx4] = r;
}

extern "C" void kernel_launch(void* const* d_in, const int* in_sizes, int n_in,
                              void* d_out, int out_size, void* d_ws, size_t ws_size,
                              hipStream_t stream) {
  (void)in_sizes; (void)n_in; (void)out_size;
  const float* xy  = (const float*)d_in[1];
  const float* kW1 = (const float*)d_in[3];
  const float* kb1 = (const float*)d_in[4];
  const float* kW2 = (const float*)d_in[5];
  const float* kb2 = (const float*)d_in[6];
  const float* kW3 = (const float*)d_in[7];
  const float* kb3 = (const float*)d_in[8];
  const float* fW1 = (const float*)d_in[9];
  const float* fb1 = (const float*)d_in[10];
  const float* fW2 = (const float*)d_in[11];
  const float* fb2 = (const float*)d_in[12];
  const float* fW3 = (const float*)d_in[13];
  const float* fb3 = (const float*)d_in[14];
  const float* Wq  = (const float*)d_in[15];
  const float* bq  = (const float*)d_in[16];
  const float* Wk  = (const float*)d_in[17];
  const float* bk  = (const float*)d_in[18];
  const float* lng = (const float*)d_in[19];
  const float* lnb = (const float*)d_in[20];
  float* ws = (float*)d_ws;
  float* out = (float*)d_out;
  if (ws_size < WS_FLOATS * sizeof(float)) return;  // visible failure, no OOB

  float* V   = ws + OFF_V;
  float* MID = ws + OFF_MID;
  float* Wm  = ws + OFF_W;
  float* Wfm = ws + OFF_WF;
  float* U1K = ws + OFF_U1K;
  float* U2K = ws + OFF_U2K;
  float* U1F = ws + OFF_U1F;
  float* U2F = ws + OFF_U2F;
  float* GP  = ws + OFF_GP;
  float* SP  = ws + OFF_SP;
  float* LNP = ws + OFF_LNP;
  float* ZU  = ws + OFF_ZU;
  float* W1v = ws + OFF_W1;
  float* CS  = ws + OFF_CS;
  // overlays (temporally disjoint with original owners)
  float* G    = ws + OFF_U1K;            // 32768 (U tables dead after k_mlp2)
  float* SV   = ws + OFF_U1F;            // 512
  float* PM   = ws + OFF_GP + 524288;    // 131072 (upper half of GP; GP dead after k_gred)
  float* RP   = ws + OFF_SP;             // 2048  (SP dead after k_gred)
  ushort* WbfT = (ushort*)(ws + OFF_V);  // 1024x2048 bf16 (V dead after k_y)
  ushort* ZbfT = (ushort*)(ws + OFF_MID);// 512x2048 bf16 (MID dead after j-loop)
  float* P0   = ws + OFF_GP;             // 524288 each (GP/PM dead after k_y)
  float* P1   = ws + OFF_GP + 524288;
  float* P2   = ws + OFF_MID + 524288;   // MID upper half (lower holds ZbfT)
  float* P3   = ws + OFF_ZU;             // ZU f32 dead after k_cvtT(Z)

  k_pre_u<<<dim3(4), dim3(256), 0, stream>>>(kW1, kb1, fW1, fb1, U1K, U2K, U1F, U2F);
  k_mlp2<<<dim3(1024, 2), dim3(256), 0, stream>>>(U1K, U2K, kW2, kb2, kW3, kb3,
                                                  U1F, U2F, fW2, fb2, fW3, fb3, Wm, Wfm);
  k_colsum_p1<<<dim3(4, 16), dim3(256), 0, stream>>>(Wm, Wfm, CS);
  k_colsum_p2<<<dim3(4), dim3(256), 0, stream>>>(CS, W1v);

  k_redsum<<<dim3(32, 8), dim3(256), 0, stream>>>(xy, LNP);
  k_apply<<<dim3(1024), dim3(256), 0, stream>>>(xy, lng, lnb, LNP, nullptr, V);

  for (int j = 0; j < 2; j++) {
    k_xty<<<dim3(32, 8, 2), dim3(256), 0, stream>>>(V, V, GP, SP);
    k_gred<<<dim3(16, 8), dim3(256), 0, stream>>>(GP, SP, G, SV, 32);
    k_heads2<<<dim3(RH, 8), dim3(256), 0, stream>>>(G, SV, Wq + (size_t)j * RH * 4096, bq + j * RH * 64,
                                                    Wk + (size_t)j * RH * 4096, bk + j * RH * 64, PM, RP);
    k_mid<<<dim3(32, 8), dim3(256), 0, stream>>>(V, PM, RP, MID, LNP, DXDYf * SCALEf);
    k_apply<<<dim3(1024), dim3(256), 0, stream>>>(MID, lng + (size_t)(j + 1) * 131072,
                                                  lnb + (size_t)(j + 1) * 131072, LNP, V, V);
  }

  // final block: H = V_u^T xy_d, t = colsum(xy_d)
  k_xty<<<dim3(16, 8, 2), dim3(256), 0, stream>>>(V, xy, GP, SP);
  k_gred<<<dim3(16, 8), dim3(256), 0, stream>>>(GP, SP, G, SV, 16);
  k_heads2<<<dim3(RH, 8), dim3(256), 0, stream>>>(G, SV, Wq + (size_t)2 * RH * 4096, bq + 2 * RH * 64,
                                                  Wk + (size_t)2 * RH * 4096, bk + 2 * RH * 64, PM, RP);
  k_y<<<dim3(32, 8, 2), dim3(256), 0, stream>>>(V, PM, ZU);   // ZU/ZF f32 [2048][512]
  // bf16 transposed copies (V, MID regions now dead)
  k_cvtT<<<dim3(16, 16, 2), dim3(256), 0, stream>>>(Wm, Wfm, 1024, WbfT, 1024);
  k_cvtT<<<dim3(8, 32, 1), dim3(256), 0, stream>>>(ZU, nullptr, 512, ZbfT, 0);
  k_final_mfma<<<dim3(16, 8, 4), dim3(256), 0, stream>>>(WbfT, ZbfT, P0, P1, P2, P3);
  k_final_red<<<dim3(512), dim3(256), 0, stream>>>(P0, P1, P2, P3, W1v, RP, out);
}